// Round 4
// baseline (8499.496 us; speedup 1.0000x reference)
//
#include <hip/hip_runtime.h>
#include <hip/hip_bf16.h>

#define DEV __device__ __forceinline__

DEV float cvt(float v) { return v; }
DEV float cvt(__hip_bfloat16 v) { return __bfloat162float(v); }

DEV void storev(float* p, float v) { *p = v; }
DEV void storev(__hip_bfloat16* p, float v) { *p = __float2bfloat16(v); }

// Fused: 3x3 SAME conv (cross-correlation) + bias + ReLU + 2x2/2 maxpool (VALID).
// One thread-item = (TC couts) x (one pooled pixel). f32 weights staged in LDS.
// InT is the ACTUAL stored dtype of this layer's input (f32 for model inputs,
// bf16 for our own intermediates) — R3's bug was conflating these via a probe.
template<typename InT, int CIN, int COUT, int HIN, int WIN, int G, int TC, typename OutT>
__global__ __launch_bounds__(256)
void conv_pool_kernel(const InT* __restrict__ xa, const InT* __restrict__ xb,
                      const int n_split,
                      const float* __restrict__ w, const float* __restrict__ bias,
                      OutT* __restrict__ out)
{
    constexpr int PH = HIN / 2, PW = WIN / 2;     // pooled dims (VALID)
    constexpr int NP = PH * PW;
    constexpr int NSG = G / TC;
    constexpr int WSZ = G * CIN * 9;
    __shared__ float sw[WSZ];

    const int ngroups = COUT / G;
    const int n  = blockIdx.x / ngroups;
    const int cg = blockIdx.x % ngroups;

    for (int i = threadIdx.x; i < WSZ; i += 256)
        sw[i] = w[(size_t)cg * WSZ + i];
    __syncthreads();

    const InT* xin = (n < n_split)
        ? xa + (size_t)n * (CIN * HIN * WIN)
        : xb + (size_t)(n - n_split) * (CIN * HIN * WIN);

    constexpr int NITEMS = NSG * NP;
    for (int it = threadIdx.x; it < NITEMS; it += 256) {
        const int sg = it / NP;
        const int p  = it % NP;
        const int py = p / PW, px = p % PW;
        const int y0 = 2 * py - 1, x0 = 2 * px - 1;   // 4x4 input window origin

        int yy[4], xx[4];
        bool ym[4], xm[4];
        #pragma unroll
        for (int r = 0; r < 4; ++r) {
            yy[r] = y0 + r; ym[r] = (yy[r] >= 0) && (yy[r] < HIN);
            xx[r] = x0 + r; xm[r] = (xx[r] >= 0) && (xx[r] < WIN);
        }

        float acc[TC][4];
        #pragma unroll
        for (int t = 0; t < TC; ++t)
            #pragma unroll
            for (int d = 0; d < 4; ++d) acc[t][d] = 0.f;

        const float* wbase = &sw[sg * TC * CIN * 9];
        for (int ci = 0; ci < CIN; ++ci) {
            const InT* ip = xin + (size_t)ci * (HIN * WIN);
            float iv[4][4];
            #pragma unroll
            for (int r = 0; r < 4; ++r)
                #pragma unroll
                for (int c = 0; c < 4; ++c)
                    iv[r][c] = (ym[r] && xm[c]) ? cvt(ip[yy[r] * WIN + xx[c]]) : 0.f;

            #pragma unroll
            for (int t = 0; t < TC; ++t) {
                const float* wp = wbase + (t * CIN + ci) * 9;
                #pragma unroll
                for (int ky = 0; ky < 3; ++ky)
                    #pragma unroll
                    for (int kx = 0; kx < 3; ++kx) {
                        const float wv = wp[ky * 3 + kx];
                        acc[t][0] = fmaf(wv, iv[ky    ][kx    ], acc[t][0]);
                        acc[t][1] = fmaf(wv, iv[ky    ][kx + 1], acc[t][1]);
                        acc[t][2] = fmaf(wv, iv[ky + 1][kx    ], acc[t][2]);
                        acc[t][3] = fmaf(wv, iv[ky + 1][kx + 1], acc[t][3]);
                    }
            }
        }

        #pragma unroll
        for (int t = 0; t < TC; ++t) {
            const int co = cg * G + sg * TC + t;
            const float b = bias[co];
            float m = fmaxf(fmaxf(acc[t][0], acc[t][1]), fmaxf(acc[t][2], acc[t][3]));
            float v = fmaxf(m + b, 0.f);   // relu(max(conv)+b) == max(relu(conv+b))
            storev(&out[((size_t)n * COUT + co) * NP + p], v);
        }
    }
}

// g[n][c] = mean over 25 spatial positions of f4[n][c][:]
__global__ __launch_bounds__(256)
void gap_kernel(const float* __restrict__ f4, float* __restrict__ g)
{
    const int i = blockIdx.x * 256 + threadIdx.x;
    if (i >= 400 * 512) return;
    const float* p = f4 + (size_t)i * 25;
    float s = 0.f;
    #pragma unroll
    for (int j = 0; j < 25; ++j) s += p[j];
    g[i] = s * (1.f / 25.f);
}

// proto[b][k][c] = l2norm_c( (1/cnt) * sum_n ytrain[b][n][k] * g[b*25+n][c] )
__global__ __launch_bounds__(256)
void proto_kernel(const float* __restrict__ g, const float* __restrict__ ytrain,
                  float* __restrict__ proto)
{
    const int b = blockIdx.x / 5, k = blockIdx.x % 5;
    __shared__ float sp[512];
    __shared__ float red[256];

    float yv[25];
    float cnt = 0.f;
    for (int n = 0; n < 25; ++n) {
        yv[n] = ytrain[(size_t)(b * 25 + n) * 5 + k];
        cnt += yv[n];
    }
    const float icnt = 1.f / cnt;

    for (int c = threadIdx.x; c < 512; c += 256) {
        float s = 0.f;
        for (int n = 0; n < 25; ++n)
            s += yv[n] * g[((size_t)(b * 25 + n)) * 512 + c];
        sp[c] = s * icnt;
    }
    __syncthreads();

    float ss = 0.f;
    for (int c = threadIdx.x; c < 512; c += 256) ss += sp[c] * sp[c];
    red[threadIdx.x] = ss;
    __syncthreads();
    for (int s = 128; s > 0; s >>= 1) {
        if (threadIdx.x < s) red[threadIdx.x] += red[threadIdx.x + s];
        __syncthreads();
    }
    const float inv = 1.f / fmaxf(sqrtf(red[0]), 1e-12f);
    for (int c = threadIdx.x; c < 512; c += 256)
        proto[((size_t)(b * 5 + k)) * 512 + c] = sp[c] * inv;
}

// predict[q][m] = l2norm(g[100+q]) . wc[m] + bc[m]   (q in [0,300), m in [0,64))
__global__ __launch_bounds__(64)
void predict_kernel(const float* __restrict__ g, const float* __restrict__ wc,
                    const float* __restrict__ bc, float* __restrict__ out)
{
    const int q = blockIdx.x;
    __shared__ float fq[512];
    const float* gq = g + (size_t)(100 + q) * 512;
    float ss = 0.f;
    for (int c = threadIdx.x; c < 512; c += 64) {
        const float v = gq[c];
        fq[c] = v;
        ss += v * v;
    }
    #pragma unroll
    for (int o = 32; o > 0; o >>= 1) ss += __shfl_down(ss, o);
    const float inv = 1.f / fmaxf(sqrtf(__shfl(ss, 0)), 1e-12f);
    __syncthreads();

    const int m = threadIdx.x;
    float s = bc[m];
    for (int c = 0; c < 512; ++c)
        s = fmaf(fq[c] * inv, wc[m * 512 + c], s);
    out[q * 64 + m] = s;
}

// cls[q][i][p] = (f4[100+q][:,p] / max(||.||,eps)) . proto[b][i][:]
__global__ __launch_bounds__(128)
void cls_kernel(const float* __restrict__ f4, const float* __restrict__ proto,
                float* __restrict__ outc)
{
    const int q = blockIdx.x;     // 0..299 ; b = q/75
    const int b = q / 75;
    const float* f = f4 + (size_t)(100 + q) * (512 * 25);
    for (int it = threadIdx.x; it < 125; it += 128) {
        const int i = it / 25, p = it % 25;
        const float* pr = proto + (size_t)(b * 5 + i) * 512;
        float ss = 0.f, dot = 0.f;
        for (int c = 0; c < 512; ++c) {
            const float v = f[(size_t)c * 25 + p];
            ss  = fmaf(v, v, ss);
            dot = fmaf(v, pr[c], dot);
        }
        outc[(size_t)q * 125 + it] = dot / fmaxf(sqrtf(ss), 1e-12f);
    }
}

extern "C" void kernel_launch(void* const* d_in, const int* in_sizes, int n_in,
                              void* d_out, int out_size, void* d_ws, size_t ws_size,
                              hipStream_t stream)
{
    (void)in_sizes; (void)n_in; (void)out_size; (void)ws_size;
    // All float inputs are f32 (proven: R1 bf16 interpretation -> NaN cascade).
    const float* xtrain = (const float*)d_in[0];   // (4,25,3,84,84)
    const float* xtest  = (const float*)d_in[1];   // (4,75,3,84,84)
    const float* ytrain = (const float*)d_in[2];   // (4,25,5)
    // d_in[3] = ytest (int32) — unused by the reference math
    const float* w1 = (const float*)d_in[4];
    const float* b1 = (const float*)d_in[5];
    const float* w2 = (const float*)d_in[6];
    const float* b2 = (const float*)d_in[7];
    const float* w3 = (const float*)d_in[8];
    const float* b3 = (const float*)d_in[9];
    const float* w4 = (const float*)d_in[10];
    const float* b4 = (const float*)d_in[11];
    const float* wc = (const float*)d_in[12];
    const float* bc = (const float*)d_in[13];

    char* ws = (char*)d_ws;
    // a1: conv1 out (400,64,42,42) bf16 @ [0, 90,316,800)
    // a2: conv2 out (400,64,21,21) bf16 @ [90,316,800, 112,896,000)
    // a3: conv3 out (400,128,10,10) bf16 @ [0, 10,240,000)          (reuses a1)
    // f4: conv4 out (400,512,5,5)  f32  @ [16 MiB, +20,480,000)     (reuses a1)
    // g : GAP (400,512) f32 @ 40 MiB ; proto (4,5,512) f32 @ 44 MiB (reuses a1)
    __hip_bfloat16* a1 = (__hip_bfloat16*)(ws);
    __hip_bfloat16* a2 = (__hip_bfloat16*)(ws + 90316800);
    __hip_bfloat16* a3 = (__hip_bfloat16*)(ws);
    float* f4    = (float*)(ws + 16777216);
    float* g     = (float*)(ws + 41943040);
    float* proto = (float*)(ws + 46137344);
    float* out = (float*)d_out;   // reference output dtype is float32

    conv_pool_kernel<float,          3,  64, 84, 84, 16, 4, __hip_bfloat16>
        <<<400 * 4, 256, 0, stream>>>(xtrain, xtest, 100, w1, b1, a1);
    conv_pool_kernel<__hip_bfloat16, 64,  64, 42, 42, 16, 4, __hip_bfloat16>
        <<<400 * 4, 256, 0, stream>>>(a1, a1, 400, w2, b2, a2);
    conv_pool_kernel<__hip_bfloat16, 64, 128, 21, 21, 16, 4, __hip_bfloat16>
        <<<400 * 8, 256, 0, stream>>>(a2, a2, 400, w3, b3, a3);
    conv_pool_kernel<__hip_bfloat16, 128, 512, 10, 10, 16, 4, float>
        <<<400 * 32, 256, 0, stream>>>(a3, a3, 400, w4, b4, f4);

    gap_kernel<<<800, 256, 0, stream>>>(f4, g);
    proto_kernel<<<20, 256, 0, stream>>>(g, ytrain, proto);
    predict_kernel<<<300, 64, 0, stream>>>(g, wc, bc, out);
    cls_kernel<<<300, 128, 0, stream>>>(f4, proto, out + 19200);
}

// Round 5
// 757.956 us; speedup vs baseline: 11.2137x; 11.2137x over previous
//
#include <hip/hip_runtime.h>
#include <hip/hip_bf16.h>

#define DEV __device__ __forceinline__

typedef __attribute__((ext_vector_type(8))) short bf16x8;   // 8 bf16 = 4 VGPR (MFMA A/B frag)
typedef __attribute__((ext_vector_type(4))) float f32x4;    // MFMA C/D frag

DEV unsigned short f2bf(float v) {
    union { __hip_bfloat16 b; unsigned short u; } c;
    c.b = __float2bfloat16(v);
    return c.u;
}

// ---------------------------------------------------------------------------
// Workspace layout (bytes). High-water ~142.7 MB (R0-R4 used 113 MB fine).
//   X1p: conv1-out padded NHWC (400,44,44,64) bf16   @ 0          (99,123,200)
//   X2p: conv2-out padded NHWC (400,23,23,64) bf16   @ 99,123,200 (27,084,800)
//   X3p: conv3-out padded NHWC (400,12,12,128) bf16  @126,208,000 (14,745,600)
//   W1t/W2t/W3t/W4t: MFMA-layout weights             @140,953,600..142,709,760
//   f4 (400,512,5,5) f32 @ 0 (aliases dead X1p); g @20,480,000; proto @21,299,200
// ---------------------------------------------------------------------------
#define OFF_X1P   0
#define OFF_X2P   99123200
#define OFF_X3P   126208000
#define ZFILL_B   140953600
#define OFF_W1T   140953600
#define OFF_W2T   140958720
#define OFF_W3T   141050880
#define OFF_W4T   141235200
#define OFF_F4    0
#define OFF_G     20480000
#define OFF_PROTO 21299200

// ---------------------------------------------------------------------------
// zero-fill (borders of the padded NHWC activations must be 0)
// ---------------------------------------------------------------------------
__global__ __launch_bounds__(256)
void fill_zero_kernel(uint4* __restrict__ p, long n16)
{
    long i = (long)blockIdx.x * 256 + threadIdx.x;
    if (i < n16) { uint4 z; z.x = z.y = z.z = z.w = 0; p[i] = z; }
}

// ---------------------------------------------------------------------------
// weight transforms: OIHW f32 -> bf16 MFMA A-layout
// conv1: k = cin*9 + tap (== OIHW linear), [64 cout][40]
// conv2/3/4: k = tap*CIN + cin, chunks of 32: [KC][COUT][40]
// ---------------------------------------------------------------------------
__global__ __launch_bounds__(256)
void wt1_kernel(const float* __restrict__ w, short* __restrict__ dst)
{
    int t = blockIdx.x * 256 + threadIdx.x;
    if (t >= 64 * 40) return;
    int cout = t / 40, kk = t % 40;
    float v = (kk < 27) ? w[cout * 27 + kk] : 0.f;
    dst[cout * 40 + kk] = (short)f2bf(v);
}

template<int COUT, int CIN>
__global__ __launch_bounds__(256)
void wt_tap_kernel(const float* __restrict__ w, short* __restrict__ dst)
{
    int t = blockIdx.x * 256 + threadIdx.x;
    if (t >= COUT * CIN * 9) return;
    int cout = t / (CIN * 9), k = t % (CIN * 9);
    int tap = k / CIN, cin = k % CIN;
    float v = w[((size_t)cout * CIN + cin) * 9 + tap];
    int kc = k >> 5, kin = k & 31;
    dst[((size_t)kc * COUT + cout) * 40 + kin] = (short)f2bf(v);
}

// ---------------------------------------------------------------------------
// conv1 (CIN=3, K=27 pad 32, single MFMA k-chunk): im2col panel built in LDS.
// Pixel order (pool-friendly): q = ypair*168 + x*2 + dy  (84x84 out, 512 px/block)
// ---------------------------------------------------------------------------
__global__ __launch_bounds__(256, 2)
void conv1_mfma_kernel(const float* __restrict__ xtrain, const float* __restrict__ xtest,
                       const short* __restrict__ W1t, const float* __restrict__ bias,
                       short* __restrict__ X1p)
{
    __shared__ short sr[3 * 8 * 88];     // raw input rows, bf16
    __shared__ short sp_[512 * 40];      // im2col panel [px][kpad]
    __shared__ float sb[64];

    const int tid = threadIdx.x;
    const int img = blockIdx.x / 14, blkrow = blockIdx.x % 14;
    const int yp0 = blkrow * 3;
    const float* src = (img < 100) ? xtrain + (size_t)img * (3 * 84 * 84)
                                   : xtest  + (size_t)(img - 100) * (3 * 84 * 84);
    const int wv = tid >> 6, lane = tid & 63, quad = lane >> 4, ln = lane & 15;

    for (int i = tid; i < 3 * 8 * 86; i += 256) {
        int c = i % 86, t2 = i / 86, rr = t2 % 8, cin = t2 / 8;
        int gy = 2 * yp0 - 1 + rr, gx = c - 1;
        float v = (gy >= 0 && gy < 84 && gx >= 0 && gx < 84)
                  ? src[((size_t)cin * 84 + gy) * 84 + gx] : 0.f;
        sr[(cin * 8 + rr) * 88 + c] = (short)f2bf(v);
    }
    if (tid < 64) sb[tid] = bias[tid];
    __syncthreads();

    #pragma unroll
    for (int i = 0; i < 2; ++i) {
        int q = tid + i * 256;
        int qc = (q < 504) ? q : 503;
        int ypl = qc / 168, rem = qc % 168;
        int x = rem >> 1, dy = rem & 1;
        int yl = 2 * ypl + dy;
        short* row = &sp_[q * 40];
        #pragma unroll
        for (int cin = 0; cin < 3; ++cin)
            #pragma unroll
            for (int ky = 0; ky < 3; ++ky)
                #pragma unroll
                for (int kx = 0; kx < 3; ++kx)
                    row[cin * 9 + ky * 3 + kx] = sr[(cin * 8 + yl + ky) * 88 + x + kx];
        #pragma unroll
        for (int k = 27; k < 40; ++k) row[k] = 0;
    }
    __syncthreads();

    bf16x8 af[4];
    #pragma unroll
    for (int mi = 0; mi < 4; ++mi)
        af[mi] = *(const bf16x8*)(W1t + (mi * 16 + ln) * 40 + quad * 8);

    f32x4 acc[4][8];
    #pragma unroll
    for (int mi = 0; mi < 4; ++mi)
        #pragma unroll
        for (int ni = 0; ni < 8; ++ni) acc[mi][ni] = (f32x4)0.f;

    #pragma unroll
    for (int ni = 0; ni < 8; ++ni) {
        bf16x8 b = *(const bf16x8*)(&sp_[(wv * 128 + ni * 16 + ln) * 40 + quad * 8]);
        #pragma unroll
        for (int mi = 0; mi < 4; ++mi)
            acc[mi][ni] = __builtin_amdgcn_mfma_f32_16x16x32_bf16(af[mi], b, acc[mi][ni], 0, 0, 0);
    }

    // fused 2x2 maxpool (shfl over n-quad) + bias + relu -> padded NHWC store
    #pragma unroll
    for (int mi = 0; mi < 4; ++mi)
        #pragma unroll
        for (int ni = 0; ni < 8; ++ni) {
            f32x4 a = acc[mi][ni];
            #pragma unroll
            for (int r = 0; r < 4; ++r) {
                float v = a[r];
                v = fmaxf(v, __shfl_xor(v, 1));
                v = fmaxf(v, __shfl_xor(v, 2));
                a[r] = v;
            }
            int q = wv * 128 + ni * 16 + ln;
            if ((lane & 3) == 0 && q < 504) {
                int ypl = q / 168, rem = q % 168, xg = rem >> 2;
                int cout = mi * 16 + quad * 4;
                unsigned short h[4];
                #pragma unroll
                for (int r = 0; r < 4; ++r)
                    h[r] = f2bf(fmaxf(a[r] + sb[cout + r], 0.f));
                int py = yp0 + ypl;
                size_t o = (((size_t)img * 44 + py + 1) * 44 + xg + 1) * 64 + cout;
                uint2 st; st.x = h[0] | ((unsigned)h[1] << 16); st.y = h[2] | ((unsigned)h[3] << 16);
                *(uint2*)(&X1p[o]) = st;
            }
        }
}

// ---------------------------------------------------------------------------
// conv2/conv3: MFMA implicit GEMM, input staged once in LDS (channel-last,
// +8 cin pad), weights streamed per 32-k chunk with register prefetch.
// Pixel order q = ypair*WPAIR + x*2 + dy (WPAIR rounded to mult of 4).
// ---------------------------------------------------------------------------
template<int CIN, int COUT, int NWM, int NWN, int MT, int NT, int YPB,
         int WOUT, int HPIN, int WPIN, int HPO, int WPO, int RBI>
__global__ __launch_bounds__(256, 2)
void conv_mfma_kernel(const short* __restrict__ Xp, const short* __restrict__ Wt,
                      const float* __restrict__ bias, short* __restrict__ Yp)
{
    constexpr int ROWS = 2 * YPB + 2, CSTR = CIN + 8;
    constexpr int KC = CIN * 9 / 32, CPT = CIN / 32;
    constexpr int WPAIR = (2 * WOUT + 3) / 4 * 4;
    constexpr int NSLOT = YPB * WPAIR, POOLW = WOUT / 2;
    __shared__ short sx[ROWS * WPIN * CSTR];
    __shared__ short sw[COUT * 40];
    __shared__ float sb[COUT];

    const int tid = threadIdx.x;
    const int img = blockIdx.x / RBI, blkrow = blockIdx.x % RBI;
    const int yp0 = blkrow * YPB;
    const int wv = tid >> 6, lane = tid & 63, quad = lane >> 4, ln = lane & 15;
    const int msup = (NWM == 1) ? 0 : (wv >> 1);
    const int nsup = (NWM == 1) ? wv : (wv & 1);

    const short* xsrc = Xp + ((size_t)img * HPIN + 2 * yp0) * (WPIN * CIN);
    for (int i = tid; i < ROWS * WPIN * (CIN / 8); i += 256) {
        int g = i % (CIN / 8), pc = i / (CIN / 8);
        uint4 v = *(const uint4*)(xsrc + (size_t)pc * CIN + g * 8);
        *(uint4*)(&sx[pc * CSTR + g * 8]) = v;
    }
    for (int i = tid; i * 8 < COUT * 40; i += 256)
        *(uint4*)(&sw[i * 8]) = *(const uint4*)(Wt + i * 8);
    for (int i = tid; i < COUT; i += 256) sb[i] = bias[i];

    int pbase[NT];
    #pragma unroll
    for (int ni = 0; ni < NT; ++ni) {
        int q = nsup * (NT * 16) + ni * 16 + ln;
        int qc = (q < NSLOT) ? q : (NSLOT - 1);
        int ypl = qc / WPAIR, rem = qc % WPAIR;
        int x = rem >> 1; if (x > WOUT - 1) x = WOUT - 1;
        int dy = rem & 1;
        pbase[ni] = (((2 * ypl + dy) * WPIN + x) * CSTR + quad * 8) * 2;
    }

    f32x4 acc[MT][NT];
    #pragma unroll
    for (int mi = 0; mi < MT; ++mi)
        #pragma unroll
        for (int ni = 0; ni < NT; ++ni) acc[mi][ni] = (f32x4)0.f;
    __syncthreads();

    constexpr int PFB = COUT * 80;               // bytes per W chunk
    constexpr int NPF = (PFB + 4095) / 4096;

    #pragma unroll
    for (int kc = 0; kc < KC; ++kc) {
        uint4 pf[NPF];
        if (kc + 1 < KC) {
            #pragma unroll
            for (int i = 0; i < NPF; ++i) {
                int off = (i * 256 + tid) * 16;
                if (off < PFB)
                    pf[i] = *(const uint4*)((const char*)Wt + (size_t)(kc + 1) * PFB + off);
            }
        }
        bf16x8 af[MT];
        #pragma unroll
        for (int mi = 0; mi < MT; ++mi)
            af[mi] = *(const bf16x8*)(&sw[(msup * 64 + mi * 16 + ln) * 40 + quad * 8]);

        const int tap = kc / CPT, cb = (kc % CPT) * 32;
        const int ky = tap / 3, kx = tap % 3;
        const int koff = ((ky * WPIN + kx) * CSTR + cb) * 2;
        bf16x8 bfr[NT];
        #pragma unroll
        for (int ni = 0; ni < NT; ++ni)
            bfr[ni] = *(const bf16x8*)((const char*)sx + pbase[ni] + koff);

        #pragma unroll
        for (int mi = 0; mi < MT; ++mi)
            #pragma unroll
            for (int ni = 0; ni < NT; ++ni)
                acc[mi][ni] = __builtin_amdgcn_mfma_f32_16x16x32_bf16(af[mi], bfr[ni], acc[mi][ni], 0, 0, 0);

        if (kc + 1 < KC) {
            __syncthreads();
            #pragma unroll
            for (int i = 0; i < NPF; ++i) {
                int off = (i * 256 + tid) * 16;
                if (off < PFB) *(uint4*)((char*)sw + off) = pf[i];
            }
            __syncthreads();
        }
    }

    #pragma unroll
    for (int mi = 0; mi < MT; ++mi)
        #pragma unroll
        for (int ni = 0; ni < NT; ++ni) {
            f32x4 a = acc[mi][ni];
            #pragma unroll
            for (int r = 0; r < 4; ++r) {
                float v = a[r];
                v = fmaxf(v, __shfl_xor(v, 1));
                v = fmaxf(v, __shfl_xor(v, 2));
                a[r] = v;
            }
            int q = nsup * (NT * 16) + ni * 16 + ln;
            if ((lane & 3) == 0 && q < NSLOT) {
                int ypl = q / WPAIR, rem = q % WPAIR, xg = rem >> 2;
                if (xg < POOLW) {
                    int cout = msup * 64 + mi * 16 + quad * 4;
                    unsigned short h[4];
                    #pragma unroll
                    for (int r = 0; r < 4; ++r)
                        h[r] = f2bf(fmaxf(a[r] + sb[cout + r], 0.f));
                    int py = yp0 + ypl;
                    size_t o = (((size_t)img * HPO + py + 1) * WPO + xg + 1) * COUT + cout;
                    uint2 st; st.x = h[0] | ((unsigned)h[1] << 16); st.y = h[2] | ((unsigned)h[3] << 16);
                    *(uint2*)(&Yp[o]) = st;
                }
            }
        }
}

// ---------------------------------------------------------------------------
// conv4: B-fragments straight from pre-padded global NHWC (400,12,12,128).
// grid = pair(200) * 4 m-blocks; block 4 waves (2 msup x 2 nsup), wave 64x112.
// Epilogue: pool + bias + relu -> f4 NCHW f32 (400,512,5,5).
// ---------------------------------------------------------------------------
__global__ __launch_bounds__(256, 2)
void conv4_mfma_kernel(const short* __restrict__ X3p, const short* __restrict__ W4t,
                       const float* __restrict__ bias, float* __restrict__ f4)
{
    __shared__ short sw[128 * 40];
    __shared__ float sb[128];
    const int tid = threadIdx.x;
    const int mb = blockIdx.x & 3, pair = blockIdx.x >> 2;
    const int wv = tid >> 6, lane = tid & 63, quad = lane >> 4, ln = lane & 15;
    const int msup = wv >> 1, nsup = wv & 1;

    for (int i = tid; i * 8 < 128 * 40; i += 256)
        *(uint4*)(&sw[i * 8]) = *(const uint4*)(W4t + (size_t)(mb * 128) * 40 + i * 8);
    for (int i = tid; i < 128; i += 256) sb[i] = bias[mb * 128 + i];

    size_t bbase[7];
    #pragma unroll
    for (int ni = 0; ni < 7; ++ni) {
        int q = nsup * 112 + ni * 16 + ln;
        int imgl = q / 112, p = q % 112;
        int pc = (p < 100) ? p : 99;
        int yp = pc / 20, rem = pc % 20;
        int y = 2 * yp + (rem & 1), x = rem >> 1;
        int img = pair * 2 + imgl;
        bbase[ni] = (((size_t)img * 12 + y) * 12 + x) * 128 + quad * 8;
    }

    f32x4 acc[4][7];
    #pragma unroll
    for (int mi = 0; mi < 4; ++mi)
        #pragma unroll
        for (int ni = 0; ni < 7; ++ni) acc[mi][ni] = (f32x4)0.f;
    __syncthreads();

    #pragma unroll
    for (int kc = 0; kc < 36; ++kc) {
        uint4 pf[3];
        if (kc + 1 < 36) {
            #pragma unroll
            for (int i = 0; i < 3; ++i) {
                int off = (i * 256 + tid) * 16;
                if (off < 10240)
                    pf[i] = *(const uint4*)((const char*)W4t + ((size_t)(kc + 1) * 512 + mb * 128) * 80 + off);
            }
        }
        const int tap = kc >> 2, cb = (kc & 3) * 32;
        const int ky = tap / 3, kx = tap % 3;
        bf16x8 bfr[7];
        #pragma unroll
        for (int ni = 0; ni < 7; ++ni)
            bfr[ni] = *(const bf16x8*)(X3p + bbase[ni] + ((ky * 12 + kx) * 128 + cb));
        bf16x8 af[4];
        #pragma unroll
        for (int mi = 0; mi < 4; ++mi)
            af[mi] = *(const bf16x8*)(&sw[(msup * 64 + mi * 16 + ln) * 40 + quad * 8]);
        #pragma unroll
        for (int mi = 0; mi < 4; ++mi)
            #pragma unroll
            for (int ni = 0; ni < 7; ++ni)
                acc[mi][ni] = __builtin_amdgcn_mfma_f32_16x16x32_bf16(af[mi], bfr[ni], acc[mi][ni], 0, 0, 0);
        if (kc + 1 < 36) {
            __syncthreads();
            #pragma unroll
            for (int i = 0; i < 3; ++i) {
                int off = (i * 256 + tid) * 16;
                if (off < 10240) *(uint4*)((char*)sw + off) = pf[i];
            }
            __syncthreads();
        }
    }

    #pragma unroll
    for (int mi = 0; mi < 4; ++mi)
        #pragma unroll
        for (int ni = 0; ni < 7; ++ni) {
            f32x4 a = acc[mi][ni];
            #pragma unroll
            for (int r = 0; r < 4; ++r) {
                float v = a[r];
                v = fmaxf(v, __shfl_xor(v, 1));
                v = fmaxf(v, __shfl_xor(v, 2));
                a[r] = v;
            }
            int q = nsup * 112 + ni * 16 + ln;
            if ((lane & 3) == 0) {
                int imgl = q / 112, p = q % 112;
                if (p < 100) {
                    int yp = p / 20, rem = p % 20, xg = rem >> 2;
                    int img = pair * 2 + imgl;
                    int cl = msup * 64 + mi * 16 + quad * 4;
                    #pragma unroll
                    for (int r = 0; r < 4; ++r) {
                        float v = fmaxf(a[r] + sb[cl + r], 0.f);
                        f4[((size_t)img * 512 + mb * 128 + cl + r) * 25 + yp * 5 + xg] = v;
                    }
                }
            }
        }
}

// ---------------------------------------------------------------------------
// heads (f4 NCHW f32 -> g, proto, predict, cls)
// ---------------------------------------------------------------------------
__global__ __launch_bounds__(256)
void gap_kernel(const float* __restrict__ f4, float* __restrict__ g)
{
    const int i = blockIdx.x * 256 + threadIdx.x;
    if (i >= 400 * 512) return;
    const float* p = f4 + (size_t)i * 25;
    float s = 0.f;
    #pragma unroll
    for (int j = 0; j < 25; ++j) s += p[j];
    g[i] = s * (1.f / 25.f);
}

__global__ __launch_bounds__(256)
void proto_kernel(const float* __restrict__ g, const float* __restrict__ ytrain,
                  float* __restrict__ proto)
{
    const int b = blockIdx.x / 5, k = blockIdx.x % 5;
    __shared__ float sp[512];
    __shared__ float red[256];

    float yv[25];
    float cnt = 0.f;
    for (int n = 0; n < 25; ++n) {
        yv[n] = ytrain[(size_t)(b * 25 + n) * 5 + k];
        cnt += yv[n];
    }
    const float icnt = 1.f / cnt;

    for (int c = threadIdx.x; c < 512; c += 256) {
        float s = 0.f;
        for (int n = 0; n < 25; ++n)
            s += yv[n] * g[((size_t)(b * 25 + n)) * 512 + c];
        sp[c] = s * icnt;
    }
    __syncthreads();

    float ss = 0.f;
    for (int c = threadIdx.x; c < 512; c += 256) ss += sp[c] * sp[c];
    red[threadIdx.x] = ss;
    __syncthreads();
    for (int s = 128; s > 0; s >>= 1) {
        if (threadIdx.x < s) red[threadIdx.x] += red[threadIdx.x + s];
        __syncthreads();
    }
    const float inv = 1.f / fmaxf(sqrtf(red[0]), 1e-12f);
    for (int c = threadIdx.x; c < 512; c += 256)
        proto[((size_t)(b * 5 + k)) * 512 + c] = sp[c] * inv;
}

__global__ __launch_bounds__(64)
void predict_kernel(const float* __restrict__ g, const float* __restrict__ wc,
                    const float* __restrict__ bc, float* __restrict__ out)
{
    const int q = blockIdx.x;
    __shared__ float fq[512];
    const float* gq = g + (size_t)(100 + q) * 512;
    float ss = 0.f;
    for (int c = threadIdx.x; c < 512; c += 64) {
        const float v = gq[c];
        fq[c] = v;
        ss += v * v;
    }
    #pragma unroll
    for (int o = 32; o > 0; o >>= 1) ss += __shfl_down(ss, o);
    const float inv = 1.f / fmaxf(sqrtf(__shfl(ss, 0)), 1e-12f);
    __syncthreads();

    const int m = threadIdx.x;
    float s = bc[m];
    for (int c = 0; c < 512; ++c)
        s = fmaf(fq[c] * inv, wc[m * 512 + c], s);
    out[q * 64 + m] = s;
}

__global__ __launch_bounds__(256)
void cls_kernel(const float* __restrict__ f4, const float* __restrict__ proto,
                float* __restrict__ outc)
{
    __shared__ float sf[512 * 25];
    __shared__ float spr[5 * 512];
    const int q = blockIdx.x, b = q / 75;
    const float* f = f4 + (size_t)(100 + q) * (512 * 25);
    for (int i = threadIdx.x; i < 3200; i += 256)
        *(float4*)(&sf[i * 4]) = *(const float4*)(f + i * 4);
    const float* pb = proto + (size_t)b * 5 * 512;
    for (int i = threadIdx.x; i < 640; i += 256)
        *(float4*)(&spr[i * 4]) = *(const float4*)(pb + i * 4);
    __syncthreads();

    for (int it = threadIdx.x; it < 125; it += 256) {
        int i = it / 25, p = it % 25;
        float ss = 0.f, dot = 0.f;
        for (int c = 0; c < 512; ++c) {
            float v = sf[c * 25 + p];
            ss  = fmaf(v, v, ss);
            dot = fmaf(v, spr[i * 512 + c], dot);
        }
        outc[(size_t)q * 125 + it] = dot / fmaxf(sqrtf(ss), 1e-12f);
    }
}

// ---------------------------------------------------------------------------
extern "C" void kernel_launch(void* const* d_in, const int* in_sizes, int n_in,
                              void* d_out, int out_size, void* d_ws, size_t ws_size,
                              hipStream_t stream)
{
    (void)in_sizes; (void)n_in; (void)out_size; (void)ws_size;
    const float* xtrain = (const float*)d_in[0];
    const float* xtest  = (const float*)d_in[1];
    const float* ytrain = (const float*)d_in[2];
    const float* w1 = (const float*)d_in[4];
    const float* b1 = (const float*)d_in[5];
    const float* w2 = (const float*)d_in[6];
    const float* b2 = (const float*)d_in[7];
    const float* w3 = (const float*)d_in[8];
    const float* b3 = (const float*)d_in[9];
    const float* w4 = (const float*)d_in[10];
    const float* b4 = (const float*)d_in[11];
    const float* wc = (const float*)d_in[12];
    const float* bc = (const float*)d_in[13];

    char* ws = (char*)d_ws;
    short* X1p = (short*)(ws + OFF_X1P);
    short* X2p = (short*)(ws + OFF_X2P);
    short* X3p = (short*)(ws + OFF_X3P);
    short* W1t = (short*)(ws + OFF_W1T);
    short* W2t = (short*)(ws + OFF_W2T);
    short* W3t = (short*)(ws + OFF_W3T);
    short* W4t = (short*)(ws + OFF_W4T);
    float* f4    = (float*)(ws + OFF_F4);
    float* g     = (float*)(ws + OFF_G);
    float* proto = (float*)(ws + OFF_PROTO);
    float* out = (float*)d_out;

    // zero padded activation buffers (borders must be 0)
    {
        long n16 = ZFILL_B / 16;
        int blocks = (int)((n16 + 255) / 256);
        fill_zero_kernel<<<blocks, 256, 0, stream>>>((uint4*)ws, n16);
    }
    // weight transforms
    wt1_kernel<<<10, 256, 0, stream>>>(w1, W1t);
    wt_tap_kernel<64, 64><<<144, 256, 0, stream>>>(w2, W2t);
    wt_tap_kernel<128, 64><<<288, 256, 0, stream>>>(w3, W3t);
    wt_tap_kernel<512, 128><<<2304, 256, 0, stream>>>(w4, W4t);

    // backbone
    conv1_mfma_kernel<<<400 * 14, 256, 0, stream>>>(xtrain, xtest, W1t, b1, X1p);
    //                CIN COUT NWM NWN MT NT YPB WOUT HPIN WPIN HPO WPO RBI
    conv_mfma_kernel< 64,  64,  1,  4, 4, 4,  3,  42,  44,  44, 23, 23,  7>
        <<<400 * 7, 256, 0, stream>>>(X1p, W2t, b2, X2p);
    conv_mfma_kernel< 64, 128,  2,  2, 4, 7,  5,  21,  23,  23, 12, 12,  2>
        <<<400 * 2, 256, 0, stream>>>(X2p, W3t, b3, X3p);
    conv4_mfma_kernel<<<200 * 4, 256, 0, stream>>>(X3p, W4t, b4, f4);

    // heads
    gap_kernel<<<800, 256, 0, stream>>>(f4, g);
    proto_kernel<<<20, 256, 0, stream>>>(g, ytrain, proto);
    predict_kernel<<<300, 64, 0, stream>>>(g, wc, bc, out);
    cls_kernel<<<300, 256, 0, stream>>>(f4, proto, out + 19200);
}

// Round 6
// 714.051 us; speedup vs baseline: 11.9032x; 1.0615x over previous
//
#include <hip/hip_runtime.h>
#include <hip/hip_bf16.h>

#define DEV __device__ __forceinline__

typedef __attribute__((ext_vector_type(8))) short bf16x8;   // 8 bf16 = 4 VGPR (MFMA A/B frag)
typedef __attribute__((ext_vector_type(4))) float f32x4;    // MFMA C/D frag

DEV unsigned short f2bf(float v) {
    union { __hip_bfloat16 b; unsigned short u; } c;
    c.b = __float2bfloat16(v);
    return c.u;
}

// ---------------------------------------------------------------------------
// Workspace layout (bytes).
//   X1p: conv1-out padded NHWC (400,44,44,64) bf16   @ 0          (99,123,200)
//   X2p: conv2-out padded NHWC (400,23,23,64) bf16   @ 99,123,200 (27,084,800)
//   X3p: conv3-out padded NHWC (400,12,12,128) bf16  @126,208,000 (14,745,600)
//   W1t/W2t/W3t/W4t: MFMA-layout weights             @140,953,600..142,709,760
//   f4 NHWC (400,25,512) f32 @ 0 (aliases dead X1p); g @20,480,000; proto @21,299,200
// ---------------------------------------------------------------------------
#define OFF_X1P   0
#define OFF_X2P   99123200
#define OFF_X3P   126208000
#define OFF_W1T   140953600
#define OFF_W2T   140958720
#define OFF_W3T   141050880
#define OFF_W4T   141235200
#define OFF_F4    0
#define OFF_G     20480000
#define OFF_PROTO 21299200

// ---------------------------------------------------------------------------
// border-ring zero: only the 1-px pad frame of each padded NHWC image needs 0
// (interior is fully overwritten by the producing conv). Replaces 141 MB fill.
// ---------------------------------------------------------------------------
template<int HP, int WP, int C>
__global__ __launch_bounds__(256)
void border_zero_kernel(short* __restrict__ Xp)
{
    constexpr int RING = 2 * WP + 2 * (HP - 2);
    constexpr int U = C / 8;
    const int img = blockIdx.x;
    short* base = Xp + (size_t)img * (HP * WP * C);
    uint4 z; z.x = z.y = z.z = z.w = 0;
    for (int i = threadIdx.x; i < RING * U; i += 256) {
        int r = i / U, u = i % U;
        int y, x;
        if (r < WP)            { y = 0;      x = r; }
        else if (r < 2 * WP)   { y = HP - 1; x = r - WP; }
        else { int s = r - 2 * WP; y = 1 + (s >> 1); x = (s & 1) ? (WP - 1) : 0; }
        *(uint4*)(base + ((size_t)(y * WP + x)) * C + u * 8) = z;
    }
}

// ---------------------------------------------------------------------------
// weight transforms: OIHW f32 -> bf16 MFMA A-layout
// conv1: k = cin*9 + tap (== OIHW linear), [64 cout][40]
// conv2/3/4: k = tap*CIN + cin, chunks of 32: [KC][COUT][40] (pad cols 32..39 unused)
// ---------------------------------------------------------------------------
__global__ __launch_bounds__(256)
void wt1_kernel(const float* __restrict__ w, short* __restrict__ dst)
{
    int t = blockIdx.x * 256 + threadIdx.x;
    if (t >= 64 * 40) return;
    int cout = t / 40, kk = t % 40;
    float v = (kk < 27) ? w[cout * 27 + kk] : 0.f;
    dst[cout * 40 + kk] = (short)f2bf(v);
}

template<int COUT, int CIN>
__global__ __launch_bounds__(256)
void wt_tap_kernel(const float* __restrict__ w, short* __restrict__ dst)
{
    int t = blockIdx.x * 256 + threadIdx.x;
    if (t >= COUT * CIN * 9) return;
    int cout = t / (CIN * 9), k = t % (CIN * 9);
    int tap = k / CIN, cin = k % CIN;
    float v = w[((size_t)cout * CIN + cin) * 9 + tap];
    int kc = k >> 5, kin = k & 31;
    dst[((size_t)kc * COUT + cout) * 40 + kin] = (short)f2bf(v);
}

// ---------------------------------------------------------------------------
// conv1 (CIN=3, K=27 pad 32, single MFMA k-chunk): im2col panel built in LDS.
// ---------------------------------------------------------------------------
__global__ __launch_bounds__(256, 2)
void conv1_mfma_kernel(const float* __restrict__ xtrain, const float* __restrict__ xtest,
                       const short* __restrict__ W1t, const float* __restrict__ bias,
                       short* __restrict__ X1p)
{
    __shared__ short sr[3 * 8 * 88];     // raw input rows, bf16
    __shared__ short sp_[512 * 40];      // im2col panel [px][kpad]
    __shared__ float sb[64];

    const int tid = threadIdx.x;
    const int img = blockIdx.x / 14, blkrow = blockIdx.x % 14;
    const int yp0 = blkrow * 3;
    const float* src = (img < 100) ? xtrain + (size_t)img * (3 * 84 * 84)
                                   : xtest  + (size_t)(img - 100) * (3 * 84 * 84);
    const int wv = tid >> 6, lane = tid & 63, quad = lane >> 4, ln = lane & 15;

    for (int i = tid; i < 3 * 8 * 86; i += 256) {
        int c = i % 86, t2 = i / 86, rr = t2 % 8, cin = t2 / 8;
        int gy = 2 * yp0 - 1 + rr, gx = c - 1;
        float v = (gy >= 0 && gy < 84 && gx >= 0 && gx < 84)
                  ? src[((size_t)cin * 84 + gy) * 84 + gx] : 0.f;
        sr[(cin * 8 + rr) * 88 + c] = (short)f2bf(v);
    }
    if (tid < 64) sb[tid] = bias[tid];
    __syncthreads();

    #pragma unroll
    for (int i = 0; i < 2; ++i) {
        int q = tid + i * 256;
        int qc = (q < 504) ? q : 503;
        int ypl = qc / 168, rem = qc % 168;
        int x = rem >> 1, dy = rem & 1;
        int yl = 2 * ypl + dy;
        short* row = &sp_[q * 40];
        #pragma unroll
        for (int cin = 0; cin < 3; ++cin)
            #pragma unroll
            for (int ky = 0; ky < 3; ++ky)
                #pragma unroll
                for (int kx = 0; kx < 3; ++kx)
                    row[cin * 9 + ky * 3 + kx] = sr[(cin * 8 + yl + ky) * 88 + x + kx];
        #pragma unroll
        for (int k = 27; k < 40; ++k) row[k] = 0;
    }
    __syncthreads();

    bf16x8 af[4];
    #pragma unroll
    for (int mi = 0; mi < 4; ++mi)
        af[mi] = *(const bf16x8*)(W1t + (mi * 16 + ln) * 40 + quad * 8);

    f32x4 acc[4][8];
    #pragma unroll
    for (int mi = 0; mi < 4; ++mi)
        #pragma unroll
        for (int ni = 0; ni < 8; ++ni) acc[mi][ni] = (f32x4)0.f;

    #pragma unroll
    for (int ni = 0; ni < 8; ++ni) {
        bf16x8 b = *(const bf16x8*)(&sp_[(wv * 128 + ni * 16 + ln) * 40 + quad * 8]);
        #pragma unroll
        for (int mi = 0; mi < 4; ++mi)
            acc[mi][ni] = __builtin_amdgcn_mfma_f32_16x16x32_bf16(af[mi], b, acc[mi][ni], 0, 0, 0);
    }

    #pragma unroll
    for (int mi = 0; mi < 4; ++mi)
        #pragma unroll
        for (int ni = 0; ni < 8; ++ni) {
            f32x4 a = acc[mi][ni];
            #pragma unroll
            for (int r = 0; r < 4; ++r) {
                float v = a[r];
                v = fmaxf(v, __shfl_xor(v, 1));
                v = fmaxf(v, __shfl_xor(v, 2));
                a[r] = v;
            }
            int q = wv * 128 + ni * 16 + ln;
            if ((lane & 3) == 0 && q < 504) {
                int ypl = q / 168, rem = q % 168, xg = rem >> 2;
                int cout = mi * 16 + quad * 4;
                unsigned short h[4];
                #pragma unroll
                for (int r = 0; r < 4; ++r)
                    h[r] = f2bf(fmaxf(a[r] + sb[cout + r], 0.f));
                int py = yp0 + ypl;
                size_t o = (((size_t)img * 44 + py + 1) * 44 + xg + 1) * 64 + cout;
                uint2 st; st.x = h[0] | ((unsigned)h[1] << 16); st.y = h[2] | ((unsigned)h[3] << 16);
                *(uint2*)(&X1p[o]) = st;
            }
        }
}

// ---------------------------------------------------------------------------
// conv2/conv3: MFMA implicit GEMM, input staged once in LDS (channel-last,
// +8 cin pad), weights streamed per 32-k chunk with register prefetch.
// ---------------------------------------------------------------------------
template<int CIN, int COUT, int NWM, int NWN, int MT, int NT, int YPB,
         int WOUT, int HPIN, int WPIN, int HPO, int WPO, int RBI>
__global__ __launch_bounds__(256, 2)
void conv_mfma_kernel(const short* __restrict__ Xp, const short* __restrict__ Wt,
                      const float* __restrict__ bias, short* __restrict__ Yp)
{
    constexpr int ROWS = 2 * YPB + 2, CSTR = CIN + 8;
    constexpr int KC = CIN * 9 / 32, CPT = CIN / 32;
    constexpr int WPAIR = (2 * WOUT + 3) / 4 * 4;
    constexpr int NSLOT = YPB * WPAIR, POOLW = WOUT / 2;
    __shared__ short sx[ROWS * WPIN * CSTR];
    __shared__ short sw[COUT * 40];
    __shared__ float sb[COUT];

    const int tid = threadIdx.x;
    const int img = blockIdx.x / RBI, blkrow = blockIdx.x % RBI;
    const int yp0 = blkrow * YPB;
    const int wv = tid >> 6, lane = tid & 63, quad = lane >> 4, ln = lane & 15;
    const int msup = (NWM == 1) ? 0 : (wv >> 1);
    const int nsup = (NWM == 1) ? wv : (wv & 1);

    const short* xsrc = Xp + ((size_t)img * HPIN + 2 * yp0) * (WPIN * CIN);
    for (int i = tid; i < ROWS * WPIN * (CIN / 8); i += 256) {
        int g = i % (CIN / 8), pc = i / (CIN / 8);
        uint4 v = *(const uint4*)(xsrc + (size_t)pc * CIN + g * 8);
        *(uint4*)(&sx[pc * CSTR + g * 8]) = v;
    }
    for (int i = tid; i * 8 < COUT * 40; i += 256)
        *(uint4*)(&sw[i * 8]) = *(const uint4*)(Wt + i * 8);
    for (int i = tid; i < COUT; i += 256) sb[i] = bias[i];

    int pbase[NT];
    #pragma unroll
    for (int ni = 0; ni < NT; ++ni) {
        int q = nsup * (NT * 16) + ni * 16 + ln;
        int qc = (q < NSLOT) ? q : (NSLOT - 1);
        int ypl = qc / WPAIR, rem = qc % WPAIR;
        int x = rem >> 1; if (x > WOUT - 1) x = WOUT - 1;
        int dy = rem & 1;
        pbase[ni] = (((2 * ypl + dy) * WPIN + x) * CSTR + quad * 8) * 2;
    }

    f32x4 acc[MT][NT];
    #pragma unroll
    for (int mi = 0; mi < MT; ++mi)
        #pragma unroll
        for (int ni = 0; ni < NT; ++ni) acc[mi][ni] = (f32x4)0.f;
    __syncthreads();

    constexpr int PFB = COUT * 80;               // bytes per W chunk
    constexpr int NPF = (PFB + 4095) / 4096;

    #pragma unroll
    for (int kc = 0; kc < KC; ++kc) {
        uint4 pf[NPF];
        if (kc + 1 < KC) {
            #pragma unroll
            for (int i = 0; i < NPF; ++i) {
                int off = (i * 256 + tid) * 16;
                if (off < PFB)
                    pf[i] = *(const uint4*)((const char*)Wt + (size_t)(kc + 1) * PFB + off);
            }
        }
        bf16x8 af[MT];
        #pragma unroll
        for (int mi = 0; mi < MT; ++mi)
            af[mi] = *(const bf16x8*)(&sw[(msup * 64 + mi * 16 + ln) * 40 + quad * 8]);

        const int tap = kc / CPT, cb = (kc % CPT) * 32;
        const int ky = tap / 3, kx = tap % 3;
        const int koff = ((ky * WPIN + kx) * CSTR + cb) * 2;
        bf16x8 bfr[NT];
        #pragma unroll
        for (int ni = 0; ni < NT; ++ni)
            bfr[ni] = *(const bf16x8*)((const char*)sx + pbase[ni] + koff);

        #pragma unroll
        for (int mi = 0; mi < MT; ++mi)
            #pragma unroll
            for (int ni = 0; ni < NT; ++ni)
                acc[mi][ni] = __builtin_amdgcn_mfma_f32_16x16x32_bf16(af[mi], bfr[ni], acc[mi][ni], 0, 0, 0);

        if (kc + 1 < KC) {
            __syncthreads();
            #pragma unroll
            for (int i = 0; i < NPF; ++i) {
                int off = (i * 256 + tid) * 16;
                if (off < PFB) *(uint4*)((char*)sw + off) = pf[i];
            }
            __syncthreads();
        }
    }

    #pragma unroll
    for (int mi = 0; mi < MT; ++mi)
        #pragma unroll
        for (int ni = 0; ni < NT; ++ni) {
            f32x4 a = acc[mi][ni];
            #pragma unroll
            for (int r = 0; r < 4; ++r) {
                float v = a[r];
                v = fmaxf(v, __shfl_xor(v, 1));
                v = fmaxf(v, __shfl_xor(v, 2));
                a[r] = v;
            }
            int q = nsup * (NT * 16) + ni * 16 + ln;
            if ((lane & 3) == 0 && q < NSLOT) {
                int ypl = q / WPAIR, rem = q % WPAIR, xg = rem >> 2;
                if (xg < POOLW) {
                    int cout = msup * 64 + mi * 16 + quad * 4;
                    unsigned short h[4];
                    #pragma unroll
                    for (int r = 0; r < 4; ++r)
                        h[r] = f2bf(fmaxf(a[r] + sb[cout + r], 0.f));
                    int py = yp0 + ypl;
                    size_t o = (((size_t)img * HPO + py + 1) * WPO + xg + 1) * COUT + cout;
                    uint2 st; st.x = h[0] | ((unsigned)h[1] << 16); st.y = h[2] | ((unsigned)h[3] << 16);
                    *(uint2*)(&Yp[o]) = st;
                }
            }
        }
}

// ---------------------------------------------------------------------------
// conv4 (rewritten): block = 1 image x 128 couts (grid 1600), whole padded
// 12x12x128 image staged in LDS (CSTR=136), weights streamed per k-chunk.
// Epilogue: pool + bias + relu -> f4 NHWC f32 (400,25,512), float4 stores.
// ---------------------------------------------------------------------------
__global__ __launch_bounds__(256, 3)
void conv4_mfma_kernel(const short* __restrict__ X3p, const short* __restrict__ W4t,
                       const float* __restrict__ bias, float* __restrict__ f4)
{
    constexpr int CSTR = 136;
    __shared__ short sx[144 * CSTR];     // 39,168 B
    __shared__ short sw[128 * 40];       // 10,240 B
    __shared__ float sb[128];

    const int tid = threadIdx.x;
    const int img = blockIdx.x >> 2, mb = blockIdx.x & 3;
    const int wv = tid >> 6, lane = tid & 63, quad = lane >> 4, ln = lane & 15;
    const int msup = wv >> 1, nsup = wv & 1;   // 2x2 wave grid: 128 couts x 128 px-slots

    const short* xsrc = X3p + (size_t)img * (144 * 128);
    for (int i = tid; i < 144 * 16; i += 256) {
        int pc = i >> 4, g = i & 15;
        uint4 v = *(const uint4*)(xsrc + pc * 128 + g * 8);
        *(uint4*)(&sx[pc * CSTR + g * 8]) = v;
    }
    for (int i = tid; i * 8 < 128 * 40; i += 256)
        *(uint4*)(&sw[i * 8]) = *(const uint4*)(W4t + (size_t)(mb * 128) * 40 + i * 8);
    for (int i = tid; i < 128; i += 256) sb[i] = bias[mb * 128 + i];

    int pbase[4];
    #pragma unroll
    for (int ni = 0; ni < 4; ++ni) {
        int q = nsup * 64 + ni * 16 + ln;
        int pc = (q < 100) ? q : 99;
        int yp = pc / 20, rem = pc % 20;
        int y = 2 * yp + (rem & 1), x = rem >> 1;
        pbase[ni] = ((y * 12 + x) * CSTR + quad * 8) * 2;
    }

    f32x4 acc[4][4];
    #pragma unroll
    for (int mi = 0; mi < 4; ++mi)
        #pragma unroll
        for (int ni = 0; ni < 4; ++ni) acc[mi][ni] = (f32x4)0.f;
    __syncthreads();

    for (int kc = 0; kc < 36; ++kc) {
        uint4 pf[3];
        if (kc + 1 < 36) {
            #pragma unroll
            for (int i = 0; i < 3; ++i) {
                int off = (i * 256 + tid) * 16;
                if (off < 10240)
                    pf[i] = *(const uint4*)((const char*)W4t + ((size_t)(kc + 1) * 512 + mb * 128) * 80 + off);
            }
        }
        const int tap = kc >> 2, cb = (kc & 3) * 32;
        const int ky = tap / 3, kx = tap % 3;
        const int koff = ((ky * 12 + kx) * CSTR + cb) * 2;
        bf16x8 bfr[4];
        #pragma unroll
        for (int ni = 0; ni < 4; ++ni)
            bfr[ni] = *(const bf16x8*)((const char*)sx + pbase[ni] + koff);
        bf16x8 af[4];
        #pragma unroll
        for (int mi = 0; mi < 4; ++mi)
            af[mi] = *(const bf16x8*)(&sw[(msup * 64 + mi * 16 + ln) * 40 + quad * 8]);
        #pragma unroll
        for (int mi = 0; mi < 4; ++mi)
            #pragma unroll
            for (int ni = 0; ni < 4; ++ni)
                acc[mi][ni] = __builtin_amdgcn_mfma_f32_16x16x32_bf16(af[mi], bfr[ni], acc[mi][ni], 0, 0, 0);
        if (kc + 1 < 36) {
            __syncthreads();
            #pragma unroll
            for (int i = 0; i < 3; ++i) {
                int off = (i * 256 + tid) * 16;
                if (off < 10240) *(uint4*)((char*)sw + off) = pf[i];
            }
            __syncthreads();
        }
    }

    #pragma unroll
    for (int mi = 0; mi < 4; ++mi)
        #pragma unroll
        for (int ni = 0; ni < 4; ++ni) {
            f32x4 a = acc[mi][ni];
            #pragma unroll
            for (int r = 0; r < 4; ++r) {
                float v = a[r];
                v = fmaxf(v, __shfl_xor(v, 1));
                v = fmaxf(v, __shfl_xor(v, 2));
                a[r] = v;
            }
            int q = nsup * 64 + ni * 16 + ln;
            if ((lane & 3) == 0 && q < 100) {
                int yp = q / 20, rem = q % 20, xg = rem >> 2;
                int cl = msup * 64 + mi * 16 + quad * 4;
                f32x4 st;
                #pragma unroll
                for (int r = 0; r < 4; ++r) st[r] = fmaxf(a[r] + sb[cl + r], 0.f);
                *(f32x4*)(&f4[(((size_t)img * 25) + yp * 5 + xg) * 512 + mb * 128 + cl]) = st;
            }
        }
}

// ---------------------------------------------------------------------------
// heads (f4 NHWC f32 (400,25,512) -> g, proto, predict, cls)
// ---------------------------------------------------------------------------
__global__ __launch_bounds__(256)
void gap_kernel(const float* __restrict__ f4, float* __restrict__ g)
{
    const int img = blockIdx.x;
    for (int c = threadIdx.x; c < 512; c += 256) {
        float s = 0.f;
        #pragma unroll
        for (int p = 0; p < 25; ++p)
            s += f4[((size_t)img * 25 + p) * 512 + c];
        g[(size_t)img * 512 + c] = s * (1.f / 25.f);
    }
}

__global__ __launch_bounds__(256)
void proto_kernel(const float* __restrict__ g, const float* __restrict__ ytrain,
                  float* __restrict__ proto)
{
    const int b = blockIdx.x / 5, k = blockIdx.x % 5;
    __shared__ float sp[512];
    __shared__ float red[256];

    float yv[25];
    float cnt = 0.f;
    for (int n = 0; n < 25; ++n) {
        yv[n] = ytrain[(size_t)(b * 25 + n) * 5 + k];
        cnt += yv[n];
    }
    const float icnt = 1.f / cnt;

    for (int c = threadIdx.x; c < 512; c += 256) {
        float s = 0.f;
        for (int n = 0; n < 25; ++n)
            s += yv[n] * g[((size_t)(b * 25 + n)) * 512 + c];
        sp[c] = s * icnt;
    }
    __syncthreads();

    float ss = 0.f;
    for (int c = threadIdx.x; c < 512; c += 256) ss += sp[c] * sp[c];
    red[threadIdx.x] = ss;
    __syncthreads();
    for (int s = 128; s > 0; s >>= 1) {
        if (threadIdx.x < s) red[threadIdx.x] += red[threadIdx.x + s];
        __syncthreads();
    }
    const float inv = 1.f / fmaxf(sqrtf(red[0]), 1e-12f);
    for (int c = threadIdx.x; c < 512; c += 256)
        proto[((size_t)(b * 5 + k)) * 512 + c] = sp[c] * inv;
}

__global__ __launch_bounds__(64)
void predict_kernel(const float* __restrict__ g, const float* __restrict__ wc,
                    const float* __restrict__ bc, float* __restrict__ out)
{
    const int q = blockIdx.x;
    __shared__ float fq[512];
    const float* gq = g + (size_t)(100 + q) * 512;
    float ss = 0.f;
    for (int c = threadIdx.x; c < 512; c += 64) {
        const float v = gq[c];
        fq[c] = v;
        ss += v * v;
    }
    #pragma unroll
    for (int o = 32; o > 0; o >>= 1) ss += __shfl_down(ss, o);
    const float inv = 1.f / fmaxf(sqrtf(__shfl(ss, 0)), 1e-12f);
    __syncthreads();

    const int m = threadIdx.x;
    float s = bc[m];
    for (int c = 0; c < 512; ++c)
        s = fmaf(fq[c] * inv, wc[m * 512 + c], s);
    out[q * 64 + m] = s;
}

__global__ __launch_bounds__(256)
void cls_kernel(const float* __restrict__ f4, const float* __restrict__ proto,
                float* __restrict__ outc)
{
    __shared__ float sf[25 * 516];      // +4 pad kills 512-stride bank conflicts
    __shared__ float spr[5 * 516];
    const int q = blockIdx.x, b = q / 75;
    const float* f = f4 + (size_t)(100 + q) * (25 * 512);
    for (int i = threadIdx.x; i < 3200; i += 256) {
        int row = i >> 7, col = i & 127;
        *(float4*)(&sf[row * 516 + col * 4]) = *(const float4*)(f + row * 512 + col * 4);
    }
    const float* pb = proto + (size_t)b * 5 * 512;
    for (int i = threadIdx.x; i < 640; i += 256) {
        int row = i >> 7, col = i & 127;
        *(float4*)(&spr[row * 516 + col * 4]) = *(const float4*)(pb + row * 512 + col * 4);
    }
    __syncthreads();

    for (int it = threadIdx.x; it < 125; it += 256) {
        int i = it / 25, p = it % 25;
        const float* fp = &sf[p * 516];
        const float* pr = &spr[i * 516];
        float ss = 0.f, dot = 0.f;
        for (int c = 0; c < 512; c += 4) {
            float4 v = *(const float4*)(fp + c);
            float4 w = *(const float4*)(pr + c);
            ss  += v.x * v.x + v.y * v.y + v.z * v.z + v.w * v.w;
            dot += v.x * w.x + v.y * w.y + v.z * w.z + v.w * w.w;
        }
        outc[(size_t)q * 125 + it] = dot / fmaxf(sqrtf(ss), 1e-12f);
    }
}

// ---------------------------------------------------------------------------
extern "C" void kernel_launch(void* const* d_in, const int* in_sizes, int n_in,
                              void* d_out, int out_size, void* d_ws, size_t ws_size,
                              hipStream_t stream)
{
    (void)in_sizes; (void)n_in; (void)out_size; (void)ws_size;
    const float* xtrain = (const float*)d_in[0];
    const float* xtest  = (const float*)d_in[1];
    const float* ytrain = (const float*)d_in[2];
    const float* w1 = (const float*)d_in[4];
    const float* b1 = (const float*)d_in[5];
    const float* w2 = (const float*)d_in[6];
    const float* b2 = (const float*)d_in[7];
    const float* w3 = (const float*)d_in[8];
    const float* b3 = (const float*)d_in[9];
    const float* w4 = (const float*)d_in[10];
    const float* b4 = (const float*)d_in[11];
    const float* wc = (const float*)d_in[12];
    const float* bc = (const float*)d_in[13];

    char* ws = (char*)d_ws;
    short* X1p = (short*)(ws + OFF_X1P);
    short* X2p = (short*)(ws + OFF_X2P);
    short* X3p = (short*)(ws + OFF_X3P);
    short* W1t = (short*)(ws + OFF_W1T);
    short* W2t = (short*)(ws + OFF_W2T);
    short* W3t = (short*)(ws + OFF_W3T);
    short* W4t = (short*)(ws + OFF_W4T);
    float* f4    = (float*)(ws + OFF_F4);
    float* g     = (float*)(ws + OFF_G);
    float* proto = (float*)(ws + OFF_PROTO);
    float* out = (float*)d_out;

    // zero only the pad rings of the padded activation buffers
    border_zero_kernel<44, 44, 64><<<400, 256, 0, stream>>>(X1p);
    border_zero_kernel<23, 23, 64><<<400, 256, 0, stream>>>(X2p);
    border_zero_kernel<12, 12, 128><<<400, 256, 0, stream>>>(X3p);

    // weight transforms
    wt1_kernel<<<10, 256, 0, stream>>>(w1, W1t);
    wt_tap_kernel<64, 64><<<144, 256, 0, stream>>>(w2, W2t);
    wt_tap_kernel<128, 64><<<288, 256, 0, stream>>>(w3, W3t);
    wt_tap_kernel<512, 128><<<2304, 256, 0, stream>>>(w4, W4t);

    // backbone
    conv1_mfma_kernel<<<400 * 14, 256, 0, stream>>>(xtrain, xtest, W1t, b1, X1p);
    //                CIN COUT NWM NWN MT NT YPB WOUT HPIN WPIN HPO WPO RBI
    conv_mfma_kernel< 64,  64,  1,  4, 4, 4,  3,  42,  44,  44, 23, 23,  7>
        <<<400 * 7, 256, 0, stream>>>(X1p, W2t, b2, X2p);
    conv_mfma_kernel< 64, 128,  2,  2, 4, 7,  5,  21,  23,  23, 12, 12,  2>
        <<<400 * 2, 256, 0, stream>>>(X2p, W3t, b3, X3p);
    conv4_mfma_kernel<<<400 * 4, 256, 0, stream>>>(X3p, W4t, b4, f4);

    // heads
    gap_kernel<<<400, 256, 0, stream>>>(f4, g);
    proto_kernel<<<20, 256, 0, stream>>>(g, ytrain, proto);
    predict_kernel<<<300, 64, 0, stream>>>(g, wc, bc, out);
    cls_kernel<<<300, 256, 0, stream>>>(f4, proto, out + 19200);
}

// Round 7
// 463.605 us; speedup vs baseline: 18.3335x; 1.5402x over previous
//
#include <hip/hip_runtime.h>
#include <hip/hip_bf16.h>

#define DEV __device__ __forceinline__

typedef __attribute__((ext_vector_type(8))) short bf16x8;   // 8 bf16 = 4 VGPR (MFMA A/B frag)
typedef __attribute__((ext_vector_type(4))) float f32x4;    // MFMA C/D frag

DEV unsigned short f2bf(float v) {
    union { __hip_bfloat16 b; unsigned short u; } c;
    c.b = __float2bfloat16(v);
    return c.u;
}

// ---------------------------------------------------------------------------
// Workspace layout (bytes).
//   X1p: conv1-out padded NHWC (400,44,44,64) bf16   @ 0          (99,123,200)
//   X2p: conv2-out padded NHWC (400,23,23,64) bf16   @ 99,123,200 (27,084,800)
//   X3p: conv3-out padded NHWC (400,12,12,128) bf16  @126,208,000 (14,745,600)
//   W1t/W2t/W3t/W4t: MFMA-layout weights             @140,953,600..142,709,760
//   f4 NHWC (400,25,512) f32 @ 0 (aliases dead X1p); g @20,480,000; proto @21,299,200
// ---------------------------------------------------------------------------
#define OFF_X1P   0
#define OFF_X2P   99123200
#define OFF_X3P   126208000
#define OFF_W1T   140953600
#define OFF_W2T   140958720
#define OFF_W3T   141050880
#define OFF_W4T   141235200
#define OFF_F4    0
#define OFF_G     20480000
#define OFF_PROTO 21299200

// ---------------------------------------------------------------------------
// border-ring zero: only the 1-px pad frame of each padded NHWC image needs 0.
// ---------------------------------------------------------------------------
template<int HP, int WP, int C>
__global__ __launch_bounds__(256)
void border_zero_kernel(short* __restrict__ Xp)
{
    constexpr int RING = 2 * WP + 2 * (HP - 2);
    constexpr int U = C / 8;
    const int img = blockIdx.x;
    short* base = Xp + (size_t)img * (HP * WP * C);
    uint4 z; z.x = z.y = z.z = z.w = 0;
    for (int i = threadIdx.x; i < RING * U; i += 256) {
        int r = i / U, u = i % U;
        int y, x;
        if (r < WP)            { y = 0;      x = r; }
        else if (r < 2 * WP)   { y = HP - 1; x = r - WP; }
        else { int s = r - 2 * WP; y = 1 + (s >> 1); x = (s & 1) ? (WP - 1) : 0; }
        *(uint4*)(base + ((size_t)(y * WP + x)) * C + u * 8) = z;
    }
}

// ---------------------------------------------------------------------------
// weight transforms: OIHW f32 -> bf16 MFMA A-layout
// conv1: k = cin*9 + tap (== OIHW linear), [64 cout][40]
// conv2/3/4: k = tap*CIN + cin, chunks of 32: [KC][COUT][40]
// ---------------------------------------------------------------------------
__global__ __launch_bounds__(256)
void wt1_kernel(const float* __restrict__ w, short* __restrict__ dst)
{
    int t = blockIdx.x * 256 + threadIdx.x;
    if (t >= 64 * 40) return;
    int cout = t / 40, kk = t % 40;
    float v = (kk < 27) ? w[cout * 27 + kk] : 0.f;
    dst[cout * 40 + kk] = (short)f2bf(v);
}

template<int COUT, int CIN>
__global__ __launch_bounds__(256)
void wt_tap_kernel(const float* __restrict__ w, short* __restrict__ dst)
{
    int t = blockIdx.x * 256 + threadIdx.x;
    if (t >= COUT * CIN * 9) return;
    int cout = t / (CIN * 9), k = t % (CIN * 9);
    int tap = k / CIN, cin = k % CIN;
    float v = w[((size_t)cout * CIN + cin) * 9 + tap];
    int kc = k >> 5, kin = k & 31;
    dst[((size_t)kc * COUT + cout) * 40 + kin] = (short)f2bf(v);
}

// ---------------------------------------------------------------------------
// conv1 (CIN=3, K=27 pad 32, single MFMA k-chunk): im2col panel built in LDS.
// ---------------------------------------------------------------------------
__global__ __launch_bounds__(256, 2)
void conv1_mfma_kernel(const float* __restrict__ xtrain, const float* __restrict__ xtest,
                       const short* __restrict__ W1t, const float* __restrict__ bias,
                       short* __restrict__ X1p)
{
    __shared__ short sr[3 * 8 * 88];     // raw input rows, bf16
    __shared__ short sp_[512 * 40];      // im2col panel [px][kpad]
    __shared__ float sb[64];

    const int tid = threadIdx.x;
    const int img = blockIdx.x / 14, blkrow = blockIdx.x % 14;
    const int yp0 = blkrow * 3;
    const float* src = (img < 100) ? xtrain + (size_t)img * (3 * 84 * 84)
                                   : xtest  + (size_t)(img - 100) * (3 * 84 * 84);
    const int wv = tid >> 6, lane = tid & 63, quad = lane >> 4, ln = lane & 15;

    for (int i = tid; i < 3 * 8 * 86; i += 256) {
        int c = i % 86, t2 = i / 86, rr = t2 % 8, cin = t2 / 8;
        int gy = 2 * yp0 - 1 + rr, gx = c - 1;
        float v = (gy >= 0 && gy < 84 && gx >= 0 && gx < 84)
                  ? src[((size_t)cin * 84 + gy) * 84 + gx] : 0.f;
        sr[(cin * 8 + rr) * 88 + c] = (short)f2bf(v);
    }
    if (tid < 64) sb[tid] = bias[tid];
    __syncthreads();

    #pragma unroll
    for (int i = 0; i < 2; ++i) {
        int q = tid + i * 256;
        int qc = (q < 504) ? q : 503;
        int ypl = qc / 168, rem = qc % 168;
        int x = rem >> 1, dy = rem & 1;
        int yl = 2 * ypl + dy;
        short* row = &sp_[q * 40];
        #pragma unroll
        for (int cin = 0; cin < 3; ++cin)
            #pragma unroll
            for (int ky = 0; ky < 3; ++ky)
                #pragma unroll
                for (int kx = 0; kx < 3; ++kx)
                    row[cin * 9 + ky * 3 + kx] = sr[(cin * 8 + yl + ky) * 88 + x + kx];
        #pragma unroll
        for (int k = 27; k < 40; ++k) row[k] = 0;
    }
    __syncthreads();

    bf16x8 af[4];
    #pragma unroll
    for (int mi = 0; mi < 4; ++mi)
        af[mi] = *(const bf16x8*)(W1t + (mi * 16 + ln) * 40 + quad * 8);

    f32x4 acc[4][8];
    #pragma unroll
    for (int mi = 0; mi < 4; ++mi)
        #pragma unroll
        for (int ni = 0; ni < 8; ++ni) acc[mi][ni] = (f32x4)0.f;

    #pragma unroll
    for (int ni = 0; ni < 8; ++ni) {
        bf16x8 b = *(const bf16x8*)(&sp_[(wv * 128 + ni * 16 + ln) * 40 + quad * 8]);
        #pragma unroll
        for (int mi = 0; mi < 4; ++mi)
            acc[mi][ni] = __builtin_amdgcn_mfma_f32_16x16x32_bf16(af[mi], b, acc[mi][ni], 0, 0, 0);
    }

    #pragma unroll
    for (int mi = 0; mi < 4; ++mi)
        #pragma unroll
        for (int ni = 0; ni < 8; ++ni) {
            f32x4 a = acc[mi][ni];
            #pragma unroll
            for (int r = 0; r < 4; ++r) {
                float v = a[r];
                v = fmaxf(v, __shfl_xor(v, 1));
                v = fmaxf(v, __shfl_xor(v, 2));
                a[r] = v;
            }
            int q = wv * 128 + ni * 16 + ln;
            if ((lane & 3) == 0 && q < 504) {
                int ypl = q / 168, rem = q % 168, xg = rem >> 2;
                int cout = mi * 16 + quad * 4;
                unsigned short h[4];
                #pragma unroll
                for (int r = 0; r < 4; ++r)
                    h[r] = f2bf(fmaxf(a[r] + sb[cout + r], 0.f));
                int py = yp0 + ypl;
                size_t o = (((size_t)img * 44 + py + 1) * 44 + xg + 1) * 64 + cout;
                uint2 st; st.x = h[0] | ((unsigned)h[1] << 16); st.y = h[2] | ((unsigned)h[3] << 16);
                *(uint2*)(&X1p[o]) = st;
            }
        }
}

// ---------------------------------------------------------------------------
// conv2/conv3: MFMA implicit GEMM. Input staged once in LDS; A-fragments read
// DIRECTLY FROM GLOBAL (L2-resident, coalesced) with 1-deep register ping-pong
// prefetch for both af (global) and bfr (LDS). NO barriers in the K-loop.
// ---------------------------------------------------------------------------
template<int CIN, int COUT, int NWM, int NWN, int MT, int NT, int YPB,
         int WOUT, int HPIN, int WPIN, int HPO, int WPO, int RBI>
__global__ __launch_bounds__(256, 2)
void conv_mfma_kernel(const short* __restrict__ Xp, const short* __restrict__ Wt,
                      const float* __restrict__ bias, short* __restrict__ Yp)
{
    constexpr int ROWS = 2 * YPB + 2, CSTR = CIN + 8;
    constexpr int KC = CIN * 9 / 32, CPT = CIN / 32;
    constexpr int WPAIR = (2 * WOUT + 3) / 4 * 4;
    constexpr int NSLOT = YPB * WPAIR, POOLW = WOUT / 2;
    __shared__ short sx[ROWS * WPIN * CSTR];
    __shared__ float sb[COUT];

    const int tid = threadIdx.x;
    const int img = blockIdx.x / RBI, blkrow = blockIdx.x % RBI;
    const int yp0 = blkrow * YPB;
    const int wv = tid >> 6, lane = tid & 63, quad = lane >> 4, ln = lane & 15;
    const int msup = (NWM == 1) ? 0 : (wv >> 1);
    const int nsup = (NWM == 1) ? wv : (wv & 1);

    const short* xsrc = Xp + ((size_t)img * HPIN + 2 * yp0) * (WPIN * CIN);
    for (int i = tid; i < ROWS * WPIN * (CIN / 8); i += 256) {
        int g = i % (CIN / 8), pc = i / (CIN / 8);
        uint4 v = *(const uint4*)(xsrc + (size_t)pc * CIN + g * 8);
        *(uint4*)(&sx[pc * CSTR + g * 8]) = v;
    }
    for (int i = tid; i < COUT; i += 256) sb[i] = bias[i];

    int pbase[NT];
    #pragma unroll
    for (int ni = 0; ni < NT; ++ni) {
        int q = nsup * (NT * 16) + ni * 16 + ln;
        int qc = (q < NSLOT) ? q : (NSLOT - 1);
        int ypl = qc / WPAIR, rem = qc % WPAIR;
        int x = rem >> 1; if (x > WOUT - 1) x = WOUT - 1;
        int dy = rem & 1;
        pbase[ni] = (((2 * ypl + dy) * WPIN + x) * CSTR + quad * 8) * 2;
    }

    f32x4 acc[MT][NT];
    #pragma unroll
    for (int mi = 0; mi < MT; ++mi)
        #pragma unroll
        for (int ni = 0; ni < NT; ++ni) acc[mi][ni] = (f32x4)0.f;

    auto loadAF = [&](bf16x8* dst, int kc) {
        #pragma unroll
        for (int mi = 0; mi < MT; ++mi)
            dst[mi] = *(const bf16x8*)(Wt + ((size_t)kc * COUT + msup * 64 + mi * 16 + ln) * 40 + quad * 8);
    };
    auto loadBF = [&](bf16x8* dst, int kc) {
        const int tap = kc / CPT, cb = (kc % CPT) * 32;
        const int ky = tap / 3, kx = tap % 3;
        const int koff = ((ky * WPIN + kx) * CSTR + cb) * 2;
        #pragma unroll
        for (int ni = 0; ni < NT; ++ni)
            dst[ni] = *(const bf16x8*)((const char*)sx + pbase[ni] + koff);
    };

    __syncthreads();   // sx/sb ready — the ONLY barrier

    bf16x8 afA[MT], afB[MT], bfA[NT], bfB[NT];
    loadAF(afA, 0); loadBF(bfA, 0);
    for (int kc = 0; kc < KC; kc += 2) {
        loadAF(afB, kc + 1); loadBF(bfB, kc + 1);
        #pragma unroll
        for (int mi = 0; mi < MT; ++mi)
            #pragma unroll
            for (int ni = 0; ni < NT; ++ni)
                acc[mi][ni] = __builtin_amdgcn_mfma_f32_16x16x32_bf16(afA[mi], bfA[ni], acc[mi][ni], 0, 0, 0);
        if (kc + 2 < KC) { loadAF(afA, kc + 2); loadBF(bfA, kc + 2); }
        #pragma unroll
        for (int mi = 0; mi < MT; ++mi)
            #pragma unroll
            for (int ni = 0; ni < NT; ++ni)
                acc[mi][ni] = __builtin_amdgcn_mfma_f32_16x16x32_bf16(afB[mi], bfB[ni], acc[mi][ni], 0, 0, 0);
    }

    #pragma unroll
    for (int mi = 0; mi < MT; ++mi)
        #pragma unroll
        for (int ni = 0; ni < NT; ++ni) {
            f32x4 a = acc[mi][ni];
            #pragma unroll
            for (int r = 0; r < 4; ++r) {
                float v = a[r];
                v = fmaxf(v, __shfl_xor(v, 1));
                v = fmaxf(v, __shfl_xor(v, 2));
                a[r] = v;
            }
            int q = nsup * (NT * 16) + ni * 16 + ln;
            if ((lane & 3) == 0 && q < NSLOT) {
                int ypl = q / WPAIR, rem = q % WPAIR, xg = rem >> 2;
                if (xg < POOLW) {
                    int cout = msup * 64 + mi * 16 + quad * 4;
                    unsigned short h[4];
                    #pragma unroll
                    for (int r = 0; r < 4; ++r)
                        h[r] = f2bf(fmaxf(a[r] + sb[cout + r], 0.f));
                    int py = yp0 + ypl;
                    size_t o = (((size_t)img * HPO + py + 1) * WPO + xg + 1) * COUT + cout;
                    uint2 st; st.x = h[0] | ((unsigned)h[1] << 16); st.y = h[2] | ((unsigned)h[3] << 16);
                    *(uint2*)(&Yp[o]) = st;
                }
            }
        }
}

// ---------------------------------------------------------------------------
// conv4: image in LDS (CSTR=136), A-frags from global with ping-pong prefetch,
// no K-loop barriers. Epilogue: pool + bias + relu -> f4 NHWC f32 (400,25,512).
// ---------------------------------------------------------------------------
__global__ __launch_bounds__(256, 2)
void conv4_mfma_kernel(const short* __restrict__ X3p, const short* __restrict__ W4t,
                       const float* __restrict__ bias, float* __restrict__ f4)
{
    constexpr int CSTR = 136;
    __shared__ short sx[144 * CSTR];     // 39,168 B
    __shared__ float sb[128];

    const int tid = threadIdx.x;
    const int img = blockIdx.x >> 2, mb = blockIdx.x & 3;
    const int wv = tid >> 6, lane = tid & 63, quad = lane >> 4, ln = lane & 15;
    const int msup = wv >> 1, nsup = wv & 1;

    const short* xsrc = X3p + (size_t)img * (144 * 128);
    for (int i = tid; i < 144 * 16; i += 256) {
        int pc = i >> 4, g = i & 15;
        uint4 v = *(const uint4*)(xsrc + pc * 128 + g * 8);
        *(uint4*)(&sx[pc * CSTR + g * 8]) = v;
    }
    for (int i = tid; i < 128; i += 256) sb[i] = bias[mb * 128 + i];

    int pbase[4];
    #pragma unroll
    for (int ni = 0; ni < 4; ++ni) {
        int q = nsup * 64 + ni * 16 + ln;
        int pc = (q < 100) ? q : 99;
        int yp = pc / 20, rem = pc % 20;
        int y = 2 * yp + (rem & 1), x = rem >> 1;
        pbase[ni] = ((y * 12 + x) * CSTR + quad * 8) * 2;
    }

    f32x4 acc[4][4];
    #pragma unroll
    for (int mi = 0; mi < 4; ++mi)
        #pragma unroll
        for (int ni = 0; ni < 4; ++ni) acc[mi][ni] = (f32x4)0.f;

    auto loadAF = [&](bf16x8* dst, int kc) {
        #pragma unroll
        for (int mi = 0; mi < 4; ++mi)
            dst[mi] = *(const bf16x8*)(W4t + ((size_t)kc * 512 + mb * 128 + msup * 64 + mi * 16 + ln) * 40 + quad * 8);
    };
    auto loadBF = [&](bf16x8* dst, int kc) {
        const int tap = kc >> 2, cb = (kc & 3) * 32;
        const int ky = tap / 3, kx = tap % 3;
        const int koff = ((ky * 12 + kx) * CSTR + cb) * 2;
        #pragma unroll
        for (int ni = 0; ni < 4; ++ni)
            dst[ni] = *(const bf16x8*)((const char*)sx + pbase[ni] + koff);
    };

    __syncthreads();   // sx/sb ready — the ONLY barrier

    bf16x8 afA[4], afB[4], bfA[4], bfB[4];
    loadAF(afA, 0); loadBF(bfA, 0);
    for (int kc = 0; kc < 36; kc += 2) {
        loadAF(afB, kc + 1); loadBF(bfB, kc + 1);
        #pragma unroll
        for (int mi = 0; mi < 4; ++mi)
            #pragma unroll
            for (int ni = 0; ni < 4; ++ni)
                acc[mi][ni] = __builtin_amdgcn_mfma_f32_16x16x32_bf16(afA[mi], bfA[ni], acc[mi][ni], 0, 0, 0);
        if (kc + 2 < 36) { loadAF(afA, kc + 2); loadBF(bfA, kc + 2); }
        #pragma unroll
        for (int mi = 0; mi < 4; ++mi)
            #pragma unroll
            for (int ni = 0; ni < 4; ++ni)
                acc[mi][ni] = __builtin_amdgcn_mfma_f32_16x16x32_bf16(afB[mi], bfB[ni], acc[mi][ni], 0, 0, 0);
    }

    #pragma unroll
    for (int mi = 0; mi < 4; ++mi)
        #pragma unroll
        for (int ni = 0; ni < 4; ++ni) {
            f32x4 a = acc[mi][ni];
            #pragma unroll
            for (int r = 0; r < 4; ++r) {
                float v = a[r];
                v = fmaxf(v, __shfl_xor(v, 1));
                v = fmaxf(v, __shfl_xor(v, 2));
                a[r] = v;
            }
            int q = nsup * 64 + ni * 16 + ln;
            if ((lane & 3) == 0 && q < 100) {
                int yp = q / 20, rem = q % 20, xg = rem >> 2;
                int cl = msup * 64 + mi * 16 + quad * 4;
                f32x4 st;
                #pragma unroll
                for (int r = 0; r < 4; ++r) st[r] = fmaxf(a[r] + sb[cl + r], 0.f);
                *(f32x4*)(&f4[(((size_t)img * 25) + yp * 5 + xg) * 512 + mb * 128 + cl]) = st;
            }
        }
}

// ---------------------------------------------------------------------------
// heads (f4 NHWC f32 (400,25,512) -> g, proto, predict, cls)
// ---------------------------------------------------------------------------
__global__ __launch_bounds__(256)
void gap_kernel(const float* __restrict__ f4, float* __restrict__ g)
{
    const int img = blockIdx.x;
    for (int c = threadIdx.x; c < 512; c += 256) {
        float s = 0.f;
        #pragma unroll
        for (int p = 0; p < 25; ++p)
            s += f4[((size_t)img * 25 + p) * 512 + c];
        g[(size_t)img * 512 + c] = s * (1.f / 25.f);
    }
}

__global__ __launch_bounds__(256)
void proto_kernel(const float* __restrict__ g, const float* __restrict__ ytrain,
                  float* __restrict__ proto)
{
    const int b = blockIdx.x / 5, k = blockIdx.x % 5;
    __shared__ float sp[512];
    __shared__ float red[256];

    float yv[25];
    float cnt = 0.f;
    for (int n = 0; n < 25; ++n) {
        yv[n] = ytrain[(size_t)(b * 25 + n) * 5 + k];
        cnt += yv[n];
    }
    const float icnt = 1.f / cnt;

    for (int c = threadIdx.x; c < 512; c += 256) {
        float s = 0.f;
        for (int n = 0; n < 25; ++n)
            s += yv[n] * g[((size_t)(b * 25 + n)) * 512 + c];
        sp[c] = s * icnt;
    }
    __syncthreads();

    float ss = 0.f;
    for (int c = threadIdx.x; c < 512; c += 256) ss += sp[c] * sp[c];
    red[threadIdx.x] = ss;
    __syncthreads();
    for (int s = 128; s > 0; s >>= 1) {
        if (threadIdx.x < s) red[threadIdx.x] += red[threadIdx.x + s];
        __syncthreads();
    }
    const float inv = 1.f / fmaxf(sqrtf(red[0]), 1e-12f);
    for (int c = threadIdx.x; c < 512; c += 256)
        proto[((size_t)(b * 5 + k)) * 512 + c] = sp[c] * inv;
}

__global__ __launch_bounds__(64)
void predict_kernel(const float* __restrict__ g, const float* __restrict__ wc,
                    const float* __restrict__ bc, float* __restrict__ out)
{
    const int q = blockIdx.x;
    __shared__ float fq[512];
    const float* gq = g + (size_t)(100 + q) * 512;
    float ss = 0.f;
    for (int c = threadIdx.x; c < 512; c += 64) {
        const float v = gq[c];
        fq[c] = v;
        ss += v * v;
    }
    #pragma unroll
    for (int o = 32; o > 0; o >>= 1) ss += __shfl_down(ss, o);
    const float inv = 1.f / fmaxf(sqrtf(__shfl(ss, 0)), 1e-12f);
    __syncthreads();

    const int m = threadIdx.x;
    float s = bc[m];
    for (int c = 0; c < 512; ++c)
        s = fmaf(fq[c] * inv, wc[m * 512 + c], s);
    out[q * 64 + m] = s;
}

__global__ __launch_bounds__(256)
void cls_kernel(const float* __restrict__ f4, const float* __restrict__ proto,
                float* __restrict__ outc)
{
    __shared__ float sf[25 * 516];      // +4 pad kills 512-stride bank conflicts
    __shared__ float spr[5 * 516];
    const int q = blockIdx.x, b = q / 75;
    const float* f = f4 + (size_t)(100 + q) * (25 * 512);
    for (int i = threadIdx.x; i < 3200; i += 256) {
        int row = i >> 7, col = i & 127;
        *(float4*)(&sf[row * 516 + col * 4]) = *(const float4*)(f + row * 512 + col * 4);
    }
    const float* pb = proto + (size_t)b * 5 * 512;
    for (int i = threadIdx.x; i < 640; i += 256) {
        int row = i >> 7, col = i & 127;
        *(float4*)(&spr[row * 516 + col * 4]) = *(const float4*)(pb + row * 512 + col * 4);
    }
    __syncthreads();

    for (int it = threadIdx.x; it < 125; it += 256) {
        int i = it / 25, p = it % 25;
        const float* fp = &sf[p * 516];
        const float* pr = &spr[i * 516];
        float ss = 0.f, dot = 0.f;
        for (int c = 0; c < 512; c += 4) {
            float4 v = *(const float4*)(fp + c);
            float4 w = *(const float4*)(pr + c);
            ss  += v.x * v.x + v.y * v.y + v.z * v.z + v.w * v.w;
            dot += v.x * w.x + v.y * w.y + v.z * w.z + v.w * w.w;
        }
        outc[(size_t)q * 125 + it] = dot / fmaxf(sqrtf(ss), 1e-12f);
    }
}

// ---------------------------------------------------------------------------
extern "C" void kernel_launch(void* const* d_in, const int* in_sizes, int n_in,
                              void* d_out, int out_size, void* d_ws, size_t ws_size,
                              hipStream_t stream)
{
    (void)in_sizes; (void)n_in; (void)out_size; (void)ws_size;
    const float* xtrain = (const float*)d_in[0];
    const float* xtest  = (const float*)d_in[1];
    const float* ytrain = (const float*)d_in[2];
    const float* w1 = (const float*)d_in[4];
    const float* b1 = (const float*)d_in[5];
    const float* w2 = (const float*)d_in[6];
    const float* b2 = (const float*)d_in[7];
    const float* w3 = (const float*)d_in[8];
    const float* b3 = (const float*)d_in[9];
    const float* w4 = (const float*)d_in[10];
    const float* b4 = (const float*)d_in[11];
    const float* wc = (const float*)d_in[12];
    const float* bc = (const float*)d_in[13];

    char* ws = (char*)d_ws;
    short* X1p = (short*)(ws + OFF_X1P);
    short* X2p = (short*)(ws + OFF_X2P);
    short* X3p = (short*)(ws + OFF_X3P);
    short* W1t = (short*)(ws + OFF_W1T);
    short* W2t = (short*)(ws + OFF_W2T);
    short* W3t = (short*)(ws + OFF_W3T);
    short* W4t = (short*)(ws + OFF_W4T);
    float* f4    = (float*)(ws + OFF_F4);
    float* g     = (float*)(ws + OFF_G);
    float* proto = (float*)(ws + OFF_PROTO);
    float* out = (float*)d_out;

    // zero only the pad rings of the padded activation buffers
    border_zero_kernel<44, 44, 64><<<400, 256, 0, stream>>>(X1p);
    border_zero_kernel<23, 23, 64><<<400, 256, 0, stream>>>(X2p);
    border_zero_kernel<12, 12, 128><<<400, 256, 0, stream>>>(X3p);

    // weight transforms
    wt1_kernel<<<10, 256, 0, stream>>>(w1, W1t);
    wt_tap_kernel<64, 64><<<144, 256, 0, stream>>>(w2, W2t);
    wt_tap_kernel<128, 64><<<288, 256, 0, stream>>>(w3, W3t);
    wt_tap_kernel<512, 128><<<2304, 256, 0, stream>>>(w4, W4t);

    // backbone
    conv1_mfma_kernel<<<400 * 14, 256, 0, stream>>>(xtrain, xtest, W1t, b1, X1p);
    //                CIN COUT NWM NWN MT NT YPB WOUT HPIN WPIN HPO WPO RBI
    conv_mfma_kernel< 64,  64,  1,  4, 4, 4,  3,  42,  44,  44, 23, 23,  7>
        <<<400 * 7, 256, 0, stream>>>(X1p, W2t, b2, X2p);
    conv_mfma_kernel< 64, 128,  2,  2, 4, 7,  5,  21,  23,  23, 12, 12,  2>
        <<<400 * 2, 256, 0, stream>>>(X2p, W3t, b3, X3p);
    conv4_mfma_kernel<<<400 * 4, 256, 0, stream>>>(X3p, W4t, b4, f4);

    // heads
    gap_kernel<<<400, 256, 0, stream>>>(f4, g);
    proto_kernel<<<20, 256, 0, stream>>>(g, ytrain, proto);
    predict_kernel<<<300, 64, 0, stream>>>(g, wc, bc, out);
    cls_kernel<<<300, 256, 0, stream>>>(f4, proto, out + 19200);
}

// Round 8
// 399.003 us; speedup vs baseline: 21.3018x; 1.1619x over previous
//
#include <hip/hip_runtime.h>
#include <hip/hip_bf16.h>

#define DEV __device__ __forceinline__

typedef __attribute__((ext_vector_type(8))) short bf16x8;   // 8 bf16 = 4 VGPR (MFMA A/B frag)
typedef __attribute__((ext_vector_type(4))) short bf16x4;   // 4 bf16 = 2 VGPR (ds_read_b64)
typedef __attribute__((ext_vector_type(4))) float f32x4;    // MFMA C/D frag

DEV unsigned short f2bf(float v) {
    union { __hip_bfloat16 b; unsigned short u; } c;
    c.b = __float2bfloat16(v);
    return c.u;
}

// ---------------------------------------------------------------------------
// Workspace layout (bytes).
//   X1p: conv1-out padded NHWC (400,44,44,64) bf16   @ 0          (99,123,200)
//   X2p: conv2-out padded NHWC (400,23,23,64) bf16   @ 99,123,200 (27,084,800)
//   X3p: conv3-out padded NHWC (400,12,12,128) bf16  @126,208,000 (14,745,600)
//   W1t/W2t/W3t/W4t: MFMA-layout weights             @140,953,600..
//   f4 NHWC (400,25,512) f32 @ 0 (aliases dead X1p); g @20,480,000; proto @21,299,200
// ---------------------------------------------------------------------------
#define OFF_X1P   0
#define OFF_X2P   99123200
#define OFF_X3P   126208000
#define OFF_W1T   140953600
#define OFF_W2T   140964096
#define OFF_W3T   141056256
#define OFF_W4T   141240576
#define OFF_F4    0
#define OFF_G     20480000
#define OFF_PROTO 21299200

// ---------------------------------------------------------------------------
// border-ring zero: only the 1-px pad frame of each padded NHWC image needs 0.
// ---------------------------------------------------------------------------
template<int HP, int WP, int C>
__global__ __launch_bounds__(256)
void border_zero_kernel(short* __restrict__ Xp)
{
    constexpr int RING = 2 * WP + 2 * (HP - 2);
    constexpr int U = C / 8;
    const int img = blockIdx.x;
    short* base = Xp + (size_t)img * (HP * WP * C);
    uint4 z; z.x = z.y = z.z = z.w = 0;
    for (int i = threadIdx.x; i < RING * U; i += 256) {
        int r = i / U, u = i % U;
        int y, x;
        if (r < WP)            { y = 0;      x = r; }
        else if (r < 2 * WP)   { y = HP - 1; x = r - WP; }
        else { int s = r - 2 * WP; y = 1 + (s >> 1); x = (s & 1) ? (WP - 1) : 0; }
        *(uint4*)(base + ((size_t)(y * WP + x)) * C + u * 8) = z;
    }
}

// ---------------------------------------------------------------------------
// weight transforms: OIHW f32 -> bf16 MFMA A-layout
// conv1: k = tap*4 + cin (cin padded 3->4), [64 cout][80] (k 36..79 zero)
// conv2/3/4: k = tap*CIN + cin, chunks of 32: [KC][COUT][40]
// ---------------------------------------------------------------------------
__global__ __launch_bounds__(256)
void wt1_kernel(const float* __restrict__ w, short* __restrict__ dst)
{
    int t = blockIdx.x * 256 + threadIdx.x;
    if (t >= 64 * 80) return;
    int cout = t / 80, kk = t % 80;
    int tap = kk >> 2, cin = kk & 3;
    float v = (tap < 9 && cin < 3) ? w[(cout * 3 + cin) * 9 + tap] : 0.f;
    dst[cout * 80 + kk] = (short)f2bf(v);
}

template<int COUT, int CIN>
__global__ __launch_bounds__(256)
void wt_tap_kernel(const float* __restrict__ w, short* __restrict__ dst)
{
    int t = blockIdx.x * 256 + threadIdx.x;
    if (t >= COUT * CIN * 9) return;
    int cout = t / (CIN * 9), k = t % (CIN * 9);
    int tap = k / CIN, cin = k % CIN;
    float v = w[((size_t)cout * CIN + cin) * 9 + tap];
    int kc = k >> 5, kin = k & 31;
    dst[((size_t)kc * COUT + cout) * 40 + kin] = (short)f2bf(v);
}

// ---------------------------------------------------------------------------
// conv1: NO im2col panel. Raw input staged in LDS as channel-last (C=4 pad),
// B-fragments assembled from 2 ds_read_b64 per (ni, chunk). K padded to 64:
// chunk0 = taps 0..7, chunk1 = tap 8 (quads>0 multiply zero weights).
// ---------------------------------------------------------------------------
__global__ __launch_bounds__(256, 2)
void conv1_mfma_kernel(const float* __restrict__ xtrain, const float* __restrict__ xtest,
                       const short* __restrict__ W1t, const float* __restrict__ bias,
                       short* __restrict__ X1p)
{
    constexpr int RSTR = 352;            // row stride (86*4 pad to 352)
    __shared__ short sr[8 * RSTR];       // 5632 B
    __shared__ float sb[64];

    const int tid = threadIdx.x;
    const int img = blockIdx.x / 14, blkrow = blockIdx.x % 14;
    const int yp0 = blkrow * 3;
    const float* src = (img < 100) ? xtrain + (size_t)img * (3 * 84 * 84)
                                   : xtest  + (size_t)(img - 100) * (3 * 84 * 84);
    const int wv = tid >> 6, lane = tid & 63, quad = lane >> 4, ln = lane & 15;

    // stage 8 rows x 86 cols, channel-last bf16 (ch3 = 0), one ds_write_b64 each
    for (int i = tid; i < 8 * 86; i += 256) {
        int r = i / 86, c = i % 86;
        int gy = 2 * yp0 - 1 + r, gx = c - 1;
        bf16x4 v = (bf16x4)0;
        if (gy >= 0 && gy < 84 && gx >= 0 && gx < 84) {
            int o = gy * 84 + gx;
            v[0] = (short)f2bf(src[o]);
            v[1] = (short)f2bf(src[7056 + o]);
            v[2] = (short)f2bf(src[14112 + o]);
        }
        *(bf16x4*)(&sr[r * RSTR + c * 4]) = v;
    }
    if (tid < 64) sb[tid] = bias[tid];

    // per-thread constant k-offsets for this quad: taps 2q, 2q+1, and tap 8
    const int t0 = 2 * quad, t1 = 2 * quad + 1;
    const int off0 = (t0 / 3) * RSTR + (t0 % 3) * 4;
    const int off1 = (t1 / 3) * RSTR + (t1 % 3) * 4;
    const int off2 = 2 * RSTR + 2 * 4;   // tap 8 = (2,2)

    // A-fragments from global (10 KB, L2-resident)
    bf16x8 af0[4], af1[4];
    #pragma unroll
    for (int mi = 0; mi < 4; ++mi) {
        af0[mi] = *(const bf16x8*)(W1t + (mi * 16 + ln) * 80 + quad * 8);
        af1[mi] = *(const bf16x8*)(W1t + (mi * 16 + ln) * 80 + 32 + quad * 8);
    }

    f32x4 acc[4][8];
    #pragma unroll
    for (int mi = 0; mi < 4; ++mi)
        #pragma unroll
        for (int ni = 0; ni < 8; ++ni) acc[mi][ni] = (f32x4)0.f;

    __syncthreads();

    #pragma unroll
    for (int ni = 0; ni < 8; ++ni) {
        int q = wv * 128 + ni * 16 + ln;
        int qc = (q < 504) ? q : 503;
        int ypl = qc / 168, rem = qc % 168;
        int x = rem >> 1, dy = rem & 1;
        int base = (2 * ypl + dy) * RSTR + x * 4;

        bf16x4 lo0 = *(const bf16x4*)(&sr[base + off0]);
        bf16x4 hi0 = *(const bf16x4*)(&sr[base + off1]);
        bf16x8 b0; 
        #pragma unroll
        for (int j = 0; j < 4; ++j) { b0[j] = lo0[j]; b0[4 + j] = hi0[j]; }
        bf16x4 lo1 = *(const bf16x4*)(&sr[base + off2]);
        bf16x8 b1;
        #pragma unroll
        for (int j = 0; j < 4; ++j) { b1[j] = lo1[j]; b1[4 + j] = lo1[j]; }

        #pragma unroll
        for (int mi = 0; mi < 4; ++mi) {
            acc[mi][ni] = __builtin_amdgcn_mfma_f32_16x16x32_bf16(af0[mi], b0, acc[mi][ni], 0, 0, 0);
            acc[mi][ni] = __builtin_amdgcn_mfma_f32_16x16x32_bf16(af1[mi], b1, acc[mi][ni], 0, 0, 0);
        }
    }

    #pragma unroll
    for (int mi = 0; mi < 4; ++mi)
        #pragma unroll
        for (int ni = 0; ni < 8; ++ni) {
            f32x4 a = acc[mi][ni];
            #pragma unroll
            for (int r = 0; r < 4; ++r) {
                float v = a[r];
                v = fmaxf(v, __shfl_xor(v, 1));
                v = fmaxf(v, __shfl_xor(v, 2));
                a[r] = v;
            }
            int q = wv * 128 + ni * 16 + ln;
            if ((lane & 3) == 0 && q < 504) {
                int ypl = q / 168, rem = q % 168, xg = rem >> 2;
                int cout = mi * 16 + quad * 4;
                unsigned short h[4];
                #pragma unroll
                for (int r = 0; r < 4; ++r)
                    h[r] = f2bf(fmaxf(a[r] + sb[cout + r], 0.f));
                int py = yp0 + ypl;
                size_t o = (((size_t)img * 44 + py + 1) * 44 + xg + 1) * 64 + cout;
                uint2 st; st.x = h[0] | ((unsigned)h[1] << 16); st.y = h[2] | ((unsigned)h[3] << 16);
                *(uint2*)(&X1p[o]) = st;
            }
        }
}

// ---------------------------------------------------------------------------
// conv2/conv3: MFMA implicit GEMM. Input staged once in LDS; A-fragments read
// DIRECTLY FROM GLOBAL (L2-resident, coalesced) with 1-deep register ping-pong
// prefetch for both af (global) and bfr (LDS). NO barriers in the K-loop.
// ---------------------------------------------------------------------------
template<int CIN, int COUT, int NWM, int NWN, int MT, int NT, int YPB,
         int WOUT, int HPIN, int WPIN, int HPO, int WPO, int RBI>
__global__ __launch_bounds__(256, 2)
void conv_mfma_kernel(const short* __restrict__ Xp, const short* __restrict__ Wt,
                      const float* __restrict__ bias, short* __restrict__ Yp)
{
    constexpr int ROWS = 2 * YPB + 2, CSTR = CIN + 8;
    constexpr int KC = CIN * 9 / 32, CPT = CIN / 32;
    constexpr int WPAIR = (2 * WOUT + 3) / 4 * 4;
    constexpr int NSLOT = YPB * WPAIR, POOLW = WOUT / 2;
    __shared__ short sx[ROWS * WPIN * CSTR];
    __shared__ float sb[COUT];

    const int tid = threadIdx.x;
    const int img = blockIdx.x / RBI, blkrow = blockIdx.x % RBI;
    const int yp0 = blkrow * YPB;
    const int wv = tid >> 6, lane = tid & 63, quad = lane >> 4, ln = lane & 15;
    const int msup = (NWM == 1) ? 0 : (wv >> 1);
    const int nsup = (NWM == 1) ? wv : (wv & 1);

    const short* xsrc = Xp + ((size_t)img * HPIN + 2 * yp0) * (WPIN * CIN);
    for (int i = tid; i < ROWS * WPIN * (CIN / 8); i += 256) {
        int g = i % (CIN / 8), pc = i / (CIN / 8);
        uint4 v = *(const uint4*)(xsrc + (size_t)pc * CIN + g * 8);
        *(uint4*)(&sx[pc * CSTR + g * 8]) = v;
    }
    for (int i = tid; i < COUT; i += 256) sb[i] = bias[i];

    int pbase[NT];
    #pragma unroll
    for (int ni = 0; ni < NT; ++ni) {
        int q = nsup * (NT * 16) + ni * 16 + ln;
        int qc = (q < NSLOT) ? q : (NSLOT - 1);
        int ypl = qc / WPAIR, rem = qc % WPAIR;
        int x = rem >> 1; if (x > WOUT - 1) x = WOUT - 1;
        int dy = rem & 1;
        pbase[ni] = (((2 * ypl + dy) * WPIN + x) * CSTR + quad * 8) * 2;
    }

    f32x4 acc[MT][NT];
    #pragma unroll
    for (int mi = 0; mi < MT; ++mi)
        #pragma unroll
        for (int ni = 0; ni < NT; ++ni) acc[mi][ni] = (f32x4)0.f;

    auto loadAF = [&](bf16x8* dst, int kc) {
        #pragma unroll
        for (int mi = 0; mi < MT; ++mi)
            dst[mi] = *(const bf16x8*)(Wt + ((size_t)kc * COUT + msup * 64 + mi * 16 + ln) * 40 + quad * 8);
    };
    auto loadBF = [&](bf16x8* dst, int kc) {
        const int tap = kc / CPT, cb = (kc % CPT) * 32;
        const int ky = tap / 3, kx = tap % 3;
        const int koff = ((ky * WPIN + kx) * CSTR + cb) * 2;
        #pragma unroll
        for (int ni = 0; ni < NT; ++ni)
            dst[ni] = *(const bf16x8*)((const char*)sx + pbase[ni] + koff);
    };

    __syncthreads();   // sx/sb ready — the ONLY barrier

    bf16x8 afA[MT], afB[MT], bfA[NT], bfB[NT];
    loadAF(afA, 0); loadBF(bfA, 0);
    for (int kc = 0; kc < KC; kc += 2) {
        loadAF(afB, kc + 1); loadBF(bfB, kc + 1);
        #pragma unroll
        for (int mi = 0; mi < MT; ++mi)
            #pragma unroll
            for (int ni = 0; ni < NT; ++ni)
                acc[mi][ni] = __builtin_amdgcn_mfma_f32_16x16x32_bf16(afA[mi], bfA[ni], acc[mi][ni], 0, 0, 0);
        if (kc + 2 < KC) { loadAF(afA, kc + 2); loadBF(bfA, kc + 2); }
        #pragma unroll
        for (int mi = 0; mi < MT; ++mi)
            #pragma unroll
            for (int ni = 0; ni < NT; ++ni)
                acc[mi][ni] = __builtin_amdgcn_mfma_f32_16x16x32_bf16(afB[mi], bfB[ni], acc[mi][ni], 0, 0, 0);
    }

    #pragma unroll
    for (int mi = 0; mi < MT; ++mi)
        #pragma unroll
        for (int ni = 0; ni < NT; ++ni) {
            f32x4 a = acc[mi][ni];
            #pragma unroll
            for (int r = 0; r < 4; ++r) {
                float v = a[r];
                v = fmaxf(v, __shfl_xor(v, 1));
                v = fmaxf(v, __shfl_xor(v, 2));
                a[r] = v;
            }
            int q = nsup * (NT * 16) + ni * 16 + ln;
            if ((lane & 3) == 0 && q < NSLOT) {
                int ypl = q / WPAIR, rem = q % WPAIR, xg = rem >> 2;
                if (xg < POOLW) {
                    int cout = msup * 64 + mi * 16 + quad * 4;
                    unsigned short h[4];
                    #pragma unroll
                    for (int r = 0; r < 4; ++r)
                        h[r] = f2bf(fmaxf(a[r] + sb[cout + r], 0.f));
                    int py = yp0 + ypl;
                    size_t o = (((size_t)img * HPO + py + 1) * WPO + xg + 1) * COUT + cout;
                    uint2 st; st.x = h[0] | ((unsigned)h[1] << 16); st.y = h[2] | ((unsigned)h[3] << 16);
                    *(uint2*)(&Yp[o]) = st;
                }
            }
        }
}

// ---------------------------------------------------------------------------
// conv4: image in LDS (CSTR=136), A-frags from global with ping-pong prefetch,
// no K-loop barriers. Epilogue: pool + bias + relu -> f4 NHWC f32 (400,25,512).
// ---------------------------------------------------------------------------
__global__ __launch_bounds__(256, 2)
void conv4_mfma_kernel(const short* __restrict__ X3p, const short* __restrict__ W4t,
                       const float* __restrict__ bias, float* __restrict__ f4)
{
    constexpr int CSTR = 136;
    __shared__ short sx[144 * CSTR];     // 39,168 B
    __shared__ float sb[128];

    const int tid = threadIdx.x;
    const int img = blockIdx.x >> 2, mb = blockIdx.x & 3;
    const int wv = tid >> 6, lane = tid & 63, quad = lane >> 4, ln = lane & 15;
    const int msup = wv >> 1, nsup = wv & 1;

    const short* xsrc = X3p + (size_t)img * (144 * 128);
    for (int i = tid; i < 144 * 16; i += 256) {
        int pc = i >> 4, g = i & 15;
        uint4 v = *(const uint4*)(xsrc + pc * 128 + g * 8);
        *(uint4*)(&sx[pc * CSTR + g * 8]) = v;
    }
    for (int i = tid; i < 128; i += 256) sb[i] = bias[mb * 128 + i];

    int pbase[4];
    #pragma unroll
    for (int ni = 0; ni < 4; ++ni) {
        int q = nsup * 64 + ni * 16 + ln;
        int pc = (q < 100) ? q : 99;
        int yp = pc / 20, rem = pc % 20;
        int y = 2 * yp + (rem & 1), x = rem >> 1;
        pbase[ni] = ((y * 12 + x) * CSTR + quad * 8) * 2;
    }

    f32x4 acc[4][4];
    #pragma unroll
    for (int mi = 0; mi < 4; ++mi)
        #pragma unroll
        for (int ni = 0; ni < 4; ++ni) acc[mi][ni] = (f32x4)0.f;

    auto loadAF = [&](bf16x8* dst, int kc) {
        #pragma unroll
        for (int mi = 0; mi < 4; ++mi)
            dst[mi] = *(const bf16x8*)(W4t + ((size_t)kc * 512 + mb * 128 + msup * 64 + mi * 16 + ln) * 40 + quad * 8);
    };
    auto loadBF = [&](bf16x8* dst, int kc) {
        const int tap = kc >> 2, cb = (kc & 3) * 32;
        const int ky = tap / 3, kx = tap % 3;
        const int koff = ((ky * 12 + kx) * CSTR + cb) * 2;
        #pragma unroll
        for (int ni = 0; ni < 4; ++ni)
            dst[ni] = *(const bf16x8*)((const char*)sx + pbase[ni] + koff);
    };

    __syncthreads();   // sx/sb ready — the ONLY barrier

    bf16x8 afA[4], afB[4], bfA[4], bfB[4];
    loadAF(afA, 0); loadBF(bfA, 0);
    for (int kc = 0; kc < 36; kc += 2) {
        loadAF(afB, kc + 1); loadBF(bfB, kc + 1);
        #pragma unroll
        for (int mi = 0; mi < 4; ++mi)
            #pragma unroll
            for (int ni = 0; ni < 4; ++ni)
                acc[mi][ni] = __builtin_amdgcn_mfma_f32_16x16x32_bf16(afA[mi], bfA[ni], acc[mi][ni], 0, 0, 0);
        if (kc + 2 < 36) { loadAF(afA, kc + 2); loadBF(bfA, kc + 2); }
        #pragma unroll
        for (int mi = 0; mi < 4; ++mi)
            #pragma unroll
            for (int ni = 0; ni < 4; ++ni)
                acc[mi][ni] = __builtin_amdgcn_mfma_f32_16x16x32_bf16(afB[mi], bfB[ni], acc[mi][ni], 0, 0, 0);
    }

    #pragma unroll
    for (int mi = 0; mi < 4; ++mi)
        #pragma unroll
        for (int ni = 0; ni < 4; ++ni) {
            f32x4 a = acc[mi][ni];
            #pragma unroll
            for (int r = 0; r < 4; ++r) {
                float v = a[r];
                v = fmaxf(v, __shfl_xor(v, 1));
                v = fmaxf(v, __shfl_xor(v, 2));
                a[r] = v;
            }
            int q = nsup * 64 + ni * 16 + ln;
            if ((lane & 3) == 0 && q < 100) {
                int yp = q / 20, rem = q % 20, xg = rem >> 2;
                int cl = msup * 64 + mi * 16 + quad * 4;
                f32x4 st;
                #pragma unroll
                for (int r = 0; r < 4; ++r) st[r] = fmaxf(a[r] + sb[cl + r], 0.f);
                *(f32x4*)(&f4[(((size_t)img * 25) + yp * 5 + xg) * 512 + mb * 128 + cl]) = st;
            }
        }
}

// ---------------------------------------------------------------------------
// heads (f4 NHWC f32 (400,25,512) -> g, proto, predict, cls)
// ---------------------------------------------------------------------------
__global__ __launch_bounds__(256)
void gap_kernel(const float* __restrict__ f4, float* __restrict__ g)
{
    const int img = blockIdx.x;
    for (int c = threadIdx.x; c < 512; c += 256) {
        float s = 0.f;
        #pragma unroll
        for (int p = 0; p < 25; ++p)
            s += f4[((size_t)img * 25 + p) * 512 + c];
        g[(size_t)img * 512 + c] = s * (1.f / 25.f);
    }
}

__global__ __launch_bounds__(256)
void proto_kernel(const float* __restrict__ g, const float* __restrict__ ytrain,
                  float* __restrict__ proto)
{
    const int b = blockIdx.x / 5, k = blockIdx.x % 5;
    __shared__ float sp[512];
    __shared__ float red[256];

    float yv[25];
    float cnt = 0.f;
    for (int n = 0; n < 25; ++n) {
        yv[n] = ytrain[(size_t)(b * 25 + n) * 5 + k];
        cnt += yv[n];
    }
    const float icnt = 1.f / cnt;

    for (int c = threadIdx.x; c < 512; c += 256) {
        float s = 0.f;
        for (int n = 0; n < 25; ++n)
            s += yv[n] * g[((size_t)(b * 25 + n)) * 512 + c];
        sp[c] = s * icnt;
    }
    __syncthreads();

    float ss = 0.f;
    for (int c = threadIdx.x; c < 512; c += 256) ss += sp[c] * sp[c];
    red[threadIdx.x] = ss;
    __syncthreads();
    for (int s = 128; s > 0; s >>= 1) {
        if (threadIdx.x < s) red[threadIdx.x] += red[threadIdx.x + s];
        __syncthreads();
    }
    const float inv = 1.f / fmaxf(sqrtf(red[0]), 1e-12f);
    for (int c = threadIdx.x; c < 512; c += 256)
        proto[((size_t)(b * 5 + k)) * 512 + c] = sp[c] * inv;
}

__global__ __launch_bounds__(64)
void predict_kernel(const float* __restrict__ g, const float* __restrict__ wc,
                    const float* __restrict__ bc, float* __restrict__ out)
{
    const int q = blockIdx.x;
    __shared__ float fq[512];
    const float* gq = g + (size_t)(100 + q) * 512;
    float ss = 0.f;
    for (int c = threadIdx.x; c < 512; c += 64) {
        const float v = gq[c];
        fq[c] = v;
        ss += v * v;
    }
    #pragma unroll
    for (int o = 32; o > 0; o >>= 1) ss += __shfl_down(ss, o);
    const float inv = 1.f / fmaxf(sqrtf(__shfl(ss, 0)), 1e-12f);
    __syncthreads();

    const int m = threadIdx.x;
    float s = bc[m];
    for (int c = 0; c < 512; ++c)
        s = fmaf(fq[c] * inv, wc[m * 512 + c], s);
    out[q * 64 + m] = s;
}

__global__ __launch_bounds__(256)
void cls_kernel(const float* __restrict__ f4, const float* __restrict__ proto,
                float* __restrict__ outc)
{
    __shared__ float sf[25 * 516];      // +4 pad kills 512-stride bank conflicts
    __shared__ float spr[5 * 516];
    const int q = blockIdx.x, b = q / 75;
    const float* f = f4 + (size_t)(100 + q) * (25 * 512);
    for (int i = threadIdx.x; i < 3200; i += 256) {
        int row = i >> 7, col = i & 127;
        *(float4*)(&sf[row * 516 + col * 4]) = *(const float4*)(f + row * 512 + col * 4);
    }
    const float* pb = proto + (size_t)b * 5 * 512;
    for (int i = threadIdx.x; i < 640; i += 256) {
        int row = i >> 7, col = i & 127;
        *(float4*)(&spr[row * 516 + col * 4]) = *(const float4*)(pb + row * 512 + col * 4);
    }
    __syncthreads();

    for (int it = threadIdx.x; it < 125; it += 256) {
        int i = it / 25, p = it % 25;
        const float* fp = &sf[p * 516];
        const float* pr = &spr[i * 516];
        float ss = 0.f, dot = 0.f;
        for (int c = 0; c < 512; c += 4) {
            float4 v = *(const float4*)(fp + c);
            float4 w = *(const float4*)(pr + c);
            ss  += v.x * v.x + v.y * v.y + v.z * v.z + v.w * v.w;
            dot += v.x * w.x + v.y * w.y + v.z * w.z + v.w * w.w;
        }
        outc[(size_t)q * 125 + it] = dot / fmaxf(sqrtf(ss), 1e-12f);
    }
}

// ---------------------------------------------------------------------------
extern "C" void kernel_launch(void* const* d_in, const int* in_sizes, int n_in,
                              void* d_out, int out_size, void* d_ws, size_t ws_size,
                              hipStream_t stream)
{
    (void)in_sizes; (void)n_in; (void)out_size; (void)ws_size;
    const float* xtrain = (const float*)d_in[0];
    const float* xtest  = (const float*)d_in[1];
    const float* ytrain = (const float*)d_in[2];
    const float* w1 = (const float*)d_in[4];
    const float* b1 = (const float*)d_in[5];
    const float* w2 = (const float*)d_in[6];
    const float* b2 = (const float*)d_in[7];
    const float* w3 = (const float*)d_in[8];
    const float* b3 = (const float*)d_in[9];
    const float* w4 = (const float*)d_in[10];
    const float* b4 = (const float*)d_in[11];
    const float* wc = (const float*)d_in[12];
    const float* bc = (const float*)d_in[13];

    char* ws = (char*)d_ws;
    short* X1p = (short*)(ws + OFF_X1P);
    short* X2p = (short*)(ws + OFF_X2P);
    short* X3p = (short*)(ws + OFF_X3P);
    short* W1t = (short*)(ws + OFF_W1T);
    short* W2t = (short*)(ws + OFF_W2T);
    short* W3t = (short*)(ws + OFF_W3T);
    short* W4t = (short*)(ws + OFF_W4T);
    float* f4    = (float*)(ws + OFF_F4);
    float* g     = (float*)(ws + OFF_G);
    float* proto = (float*)(ws + OFF_PROTO);
    float* out = (float*)d_out;

    // zero only the pad rings of the padded activation buffers
    border_zero_kernel<44, 44, 64><<<400, 256, 0, stream>>>(X1p);
    border_zero_kernel<23, 23, 64><<<400, 256, 0, stream>>>(X2p);
    border_zero_kernel<12, 12, 128><<<400, 256, 0, stream>>>(X3p);

    // weight transforms
    wt1_kernel<<<20, 256, 0, stream>>>(w1, W1t);
    wt_tap_kernel<64, 64><<<144, 256, 0, stream>>>(w2, W2t);
    wt_tap_kernel<128, 64><<<288, 256, 0, stream>>>(w3, W3t);
    wt_tap_kernel<512, 128><<<2304, 256, 0, stream>>>(w4, W4t);

    // backbone
    conv1_mfma_kernel<<<400 * 14, 256, 0, stream>>>(xtrain, xtest, W1t, b1, X1p);
    //                CIN COUT NWM NWN MT NT YPB WOUT HPIN WPIN HPO WPO RBI
    conv_mfma_kernel< 64,  64,  1,  4, 4, 4,  3,  42,  44,  44, 23, 23,  7>
        <<<400 * 7, 256, 0, stream>>>(X1p, W2t, b2, X2p);
    conv_mfma_kernel< 64, 128,  2,  2, 4, 7,  5,  21,  23,  23, 12, 12,  2>
        <<<400 * 2, 256, 0, stream>>>(X2p, W3t, b3, X3p);
    conv4_mfma_kernel<<<400 * 4, 256, 0, stream>>>(X3p, W4t, b4, f4);

    // heads
    gap_kernel<<<400, 256, 0, stream>>>(f4, g);
    proto_kernel<<<20, 256, 0, stream>>>(g, ytrain, proto);
    predict_kernel<<<300, 64, 0, stream>>>(g, wc, bc, out);
    cls_kernel<<<300, 256, 0, stream>>>(f4, proto, out + 19200);
}

// Round 9
// 330.499 us; speedup vs baseline: 25.7171x; 1.2073x over previous
//
#include <hip/hip_runtime.h>
#include <hip/hip_bf16.h>

#define DEV __device__ __forceinline__

typedef __attribute__((ext_vector_type(8))) short bf16x8;   // 8 bf16 = 4 VGPR (MFMA A/B frag)
typedef __attribute__((ext_vector_type(4))) short bf16x4;   // 4 bf16 = 2 VGPR (ds_read_b64)
typedef __attribute__((ext_vector_type(4))) float f32x4;    // MFMA C/D frag

DEV unsigned short f2bf(float v) {
    union { __hip_bfloat16 b; unsigned short u; } c;
    c.b = __float2bfloat16(v);
    return c.u;
}

// ---------------------------------------------------------------------------
// Workspace layout (bytes).
// ---------------------------------------------------------------------------
#define OFF_X1P   0
#define OFF_X2P   99123200
#define OFF_X3P   126208000
#define OFF_W1T   140953600
#define OFF_W2T   140964096
#define OFF_W3T   141056256
#define OFF_W4T   141240576
#define OFF_F4    0
#define OFF_G     20480000
#define OFF_PROTO 21299200

// ---------------------------------------------------------------------------
// border-ring zero: only the 1-px pad frame of each padded NHWC image needs 0.
// ---------------------------------------------------------------------------
template<int HP, int WP, int C>
__global__ __launch_bounds__(256)
void border_zero_kernel(short* __restrict__ Xp)
{
    constexpr int RING = 2 * WP + 2 * (HP - 2);
    constexpr int U = C / 8;
    const int img = blockIdx.x;
    short* base = Xp + (size_t)img * (HP * WP * C);
    uint4 z; z.x = z.y = z.z = z.w = 0;
    for (int i = threadIdx.x; i < RING * U; i += 256) {
        int r = i / U, u = i % U;
        int y, x;
        if (r < WP)            { y = 0;      x = r; }
        else if (r < 2 * WP)   { y = HP - 1; x = r - WP; }
        else { int s = r - 2 * WP; y = 1 + (s >> 1); x = (s & 1) ? (WP - 1) : 0; }
        *(uint4*)(base + ((size_t)(y * WP + x)) * C + u * 8) = z;
    }
}

// ---------------------------------------------------------------------------
// weight transforms: OIHW f32 -> bf16 MFMA fragment layout
// conv1: k = tap*4 + cin (cin padded 3->4), [64 cout][80] (k 36..79 zero)
// conv2/3/4: k = tap*CIN + cin, chunks of 32: [KC][COUT][40]
// ---------------------------------------------------------------------------
__global__ __launch_bounds__(256)
void wt1_kernel(const float* __restrict__ w, short* __restrict__ dst)
{
    int t = blockIdx.x * 256 + threadIdx.x;
    if (t >= 64 * 80) return;
    int cout = t / 80, kk = t % 80;
    int tap = kk >> 2, cin = kk & 3;
    float v = (tap < 9 && cin < 3) ? w[(cout * 3 + cin) * 9 + tap] : 0.f;
    dst[cout * 80 + kk] = (short)f2bf(v);
}

template<int COUT, int CIN>
__global__ __launch_bounds__(256)
void wt_tap_kernel(const float* __restrict__ w, short* __restrict__ dst)
{
    int t = blockIdx.x * 256 + threadIdx.x;
    if (t >= COUT * CIN * 9) return;
    int cout = t / (CIN * 9), k = t % (CIN * 9);
    int tap = k / CIN, cin = k % CIN;
    float v = w[((size_t)cout * CIN + cin) * 9 + tap];
    int kc = k >> 5, kin = k & 31;
    dst[((size_t)kc * COUT + cout) * 40 + kin] = (short)f2bf(v);
}

// ---------------------------------------------------------------------------
// conv1: pixels = MFMA A-operand (M dim), weights = B (N dim). Pool partners
// (q = 4g..4g+3) land in acc regs 0..3 of one lane -> pooling = 3 v_max_f32,
// no shfl, no divergent pack. Every lane stores one bf16 (cout = ln).
// ---------------------------------------------------------------------------
__global__ __launch_bounds__(256, 2)
void conv1_mfma_kernel(const float* __restrict__ xtrain, const float* __restrict__ xtest,
                       const short* __restrict__ W1t, const float* __restrict__ bias,
                       short* __restrict__ X1p)
{
    constexpr int RSTR = 352;            // row stride (86*4 pad to 352)
    __shared__ short sr[8 * RSTR];       // 5632 B
    __shared__ float sb[64];

    const int tid = threadIdx.x;
    const int img = blockIdx.x / 14, blkrow = blockIdx.x % 14;
    const int yp0 = blkrow * 3;
    const float* src = (img < 100) ? xtrain + (size_t)img * (3 * 84 * 84)
                                   : xtest  + (size_t)(img - 100) * (3 * 84 * 84);
    const int wv = tid >> 6, lane = tid & 63, quad = lane >> 4, ln = lane & 15;

    // stage 8 rows x 86 cols, channel-last bf16 (ch3 = 0), one ds_write_b64 each
    for (int i = tid; i < 8 * 86; i += 256) {
        int r = i / 86, c = i % 86;
        int gy = 2 * yp0 - 1 + r, gx = c - 1;
        bf16x4 v = (bf16x4)0;
        if (gy >= 0 && gy < 84 && gx >= 0 && gx < 84) {
            int o = gy * 84 + gx;
            v[0] = (short)f2bf(src[o]);
            v[1] = (short)f2bf(src[7056 + o]);
            v[2] = (short)f2bf(src[14112 + o]);
        }
        *(bf16x4*)(&sr[r * RSTR + c * 4]) = v;
    }
    if (tid < 64) sb[tid] = bias[tid];

    // per-thread constant k-offsets for this quad: taps 2q, 2q+1, and tap 8
    const int t0 = 2 * quad, t1 = 2 * quad + 1;
    const int off0 = (t0 / 3) * RSTR + (t0 % 3) * 4;
    const int off1 = (t1 / 3) * RSTR + (t1 % 3) * 4;
    const int off2 = 2 * RSTR + 2 * 4;   // tap 8 = (2,2)

    // weight fragments (B operand, n = cout = ln) from global (L2-resident)
    bf16x8 af0[4], af1[4];
    #pragma unroll
    for (int mi = 0; mi < 4; ++mi) {
        af0[mi] = *(const bf16x8*)(W1t + (mi * 16 + ln) * 80 + quad * 8);
        af1[mi] = *(const bf16x8*)(W1t + (mi * 16 + ln) * 80 + 32 + quad * 8);
    }

    f32x4 acc[4][8];
    #pragma unroll
    for (int mi = 0; mi < 4; ++mi)
        #pragma unroll
        for (int ni = 0; ni < 8; ++ni) acc[mi][ni] = (f32x4)0.f;

    __syncthreads();

    #pragma unroll
    for (int ni = 0; ni < 8; ++ni) {
        int q = wv * 128 + ni * 16 + ln;
        int qc = (q < 504) ? q : 503;
        int ypl = qc / 168, rem = qc % 168;
        int x = rem >> 1, dy = rem & 1;
        int base = (2 * ypl + dy) * RSTR + x * 4;

        bf16x4 lo0 = *(const bf16x4*)(&sr[base + off0]);
        bf16x4 hi0 = *(const bf16x4*)(&sr[base + off1]);
        bf16x8 b0;
        #pragma unroll
        for (int j = 0; j < 4; ++j) { b0[j] = lo0[j]; b0[4 + j] = hi0[j]; }
        bf16x4 lo1 = *(const bf16x4*)(&sr[base + off2]);
        bf16x8 b1;
        #pragma unroll
        for (int j = 0; j < 4; ++j) { b1[j] = lo1[j]; b1[4 + j] = lo1[j]; }

        #pragma unroll
        for (int mi = 0; mi < 4; ++mi) {
            acc[mi][ni] = __builtin_amdgcn_mfma_f32_16x16x32_bf16(b0, af0[mi], acc[mi][ni], 0, 0, 0);
            acc[mi][ni] = __builtin_amdgcn_mfma_f32_16x16x32_bf16(b1, af1[mi], acc[mi][ni], 0, 0, 0);
        }
    }

    // epilogue: pool = fmax of the 4 acc regs; one bf16 store per lane
    #pragma unroll
    for (int ni = 0; ni < 8; ++ni) {
        int g = wv * 32 + ni * 4 + quad;        // pooled-pixel group
        bool ok = (g < 126);
        int ypl = g / 42, xg = g % 42;
        #pragma unroll
        for (int mi = 0; mi < 4; ++mi) {
            f32x4 a = acc[mi][ni];
            float m = fmaxf(fmaxf(a[0], a[1]), fmaxf(a[2], a[3]));
            if (ok) {
                int cout = mi * 16 + ln;
                unsigned short h = f2bf(fmaxf(m + sb[cout], 0.f));
                int py = yp0 + ypl;
                size_t o = (((size_t)img * 44 + py + 1) * 44 + xg + 1) * 64 + cout;
                X1p[o] = (short)h;
            }
        }
    }
}

// ---------------------------------------------------------------------------
// conv2/conv3: MFMA implicit GEMM, pixels = A operand (M), weights = B (N).
// Input staged once in LDS; weight frags direct from global (L2); 1-deep
// register ping-pong prefetch; no K-loop barriers; reg-pool epilogue.
// ---------------------------------------------------------------------------
template<int CIN, int COUT, int NWM, int NWN, int MT, int NT, int YPB,
         int WOUT, int HPIN, int WPIN, int HPO, int WPO, int RBI>
__global__ __launch_bounds__(256, 2)
void conv_mfma_kernel(const short* __restrict__ Xp, const short* __restrict__ Wt,
                      const float* __restrict__ bias, short* __restrict__ Yp)
{
    constexpr int ROWS = 2 * YPB + 2, CSTR = CIN + 8;
    constexpr int KC = CIN * 9 / 32, CPT = CIN / 32;
    constexpr int WPAIR = (2 * WOUT + 3) / 4 * 4;
    constexpr int NSLOT = YPB * WPAIR, POOLW = WOUT / 2;
    constexpr int GPR = WPAIR / 4;       // pooled groups per ypl row
    __shared__ short sx[ROWS * WPIN * CSTR];
    __shared__ float sb[COUT];

    const int tid = threadIdx.x;
    const int img = blockIdx.x / RBI, blkrow = blockIdx.x % RBI;
    const int yp0 = blkrow * YPB;
    const int wv = tid >> 6, lane = tid & 63, quad = lane >> 4, ln = lane & 15;
    const int msup = (NWM == 1) ? 0 : (wv >> 1);
    const int nsup = (NWM == 1) ? wv : (wv & 1);

    const short* xsrc = Xp + ((size_t)img * HPIN + 2 * yp0) * (WPIN * CIN);
    for (int i = tid; i < ROWS * WPIN * (CIN / 8); i += 256) {
        int g = i % (CIN / 8), pc = i / (CIN / 8);
        uint4 v = *(const uint4*)(xsrc + (size_t)pc * CIN + g * 8);
        *(uint4*)(&sx[pc * CSTR + g * 8]) = v;
    }
    for (int i = tid; i < COUT; i += 256) sb[i] = bias[i];

    int pbase[NT];
    #pragma unroll
    for (int ni = 0; ni < NT; ++ni) {
        int q = nsup * (NT * 16) + ni * 16 + ln;
        int qc = (q < NSLOT) ? q : (NSLOT - 1);
        int ypl = qc / WPAIR, rem = qc % WPAIR;
        int x = rem >> 1; if (x > WOUT - 1) x = WOUT - 1;
        int dy = rem & 1;
        pbase[ni] = (((2 * ypl + dy) * WPIN + x) * CSTR + quad * 8) * 2;
    }

    f32x4 acc[MT][NT];
    #pragma unroll
    for (int mi = 0; mi < MT; ++mi)
        #pragma unroll
        for (int ni = 0; ni < NT; ++ni) acc[mi][ni] = (f32x4)0.f;

    auto loadAF = [&](bf16x8* dst, int kc) {
        #pragma unroll
        for (int mi = 0; mi < MT; ++mi)
            dst[mi] = *(const bf16x8*)(Wt + ((size_t)kc * COUT + msup * 64 + mi * 16 + ln) * 40 + quad * 8);
    };
    auto loadBF = [&](bf16x8* dst, int kc) {
        const int tap = kc / CPT, cb = (kc % CPT) * 32;
        const int ky = tap / 3, kx = tap % 3;
        const int koff = ((ky * WPIN + kx) * CSTR + cb) * 2;
        #pragma unroll
        for (int ni = 0; ni < NT; ++ni)
            dst[ni] = *(const bf16x8*)((const char*)sx + pbase[ni] + koff);
    };

    __syncthreads();   // sx/sb ready — the ONLY barrier

    bf16x8 afA[MT], afB[MT], bfA[NT], bfB[NT];
    loadAF(afA, 0); loadBF(bfA, 0);
    for (int kc = 0; kc < KC; kc += 2) {
        loadAF(afB, kc + 1); loadBF(bfB, kc + 1);
        #pragma unroll
        for (int mi = 0; mi < MT; ++mi)
            #pragma unroll
            for (int ni = 0; ni < NT; ++ni)
                acc[mi][ni] = __builtin_amdgcn_mfma_f32_16x16x32_bf16(bfA[ni], afA[mi], acc[mi][ni], 0, 0, 0);
        if (kc + 2 < KC) { loadAF(afA, kc + 2); loadBF(bfA, kc + 2); }
        #pragma unroll
        for (int mi = 0; mi < MT; ++mi)
            #pragma unroll
            for (int ni = 0; ni < NT; ++ni)
                acc[mi][ni] = __builtin_amdgcn_mfma_f32_16x16x32_bf16(bfB[ni], afB[mi], acc[mi][ni], 0, 0, 0);
    }

    // epilogue: pool = fmax of 4 acc regs; one bf16 store per lane
    #pragma unroll
    for (int ni = 0; ni < NT; ++ni) {
        int g = nsup * (NT * 4) + ni * 4 + quad;
        int ypl = g / GPR, xg = g % GPR;
        bool ok = (g < NSLOT / 4) && (xg < POOLW);
        #pragma unroll
        for (int mi = 0; mi < MT; ++mi) {
            f32x4 a = acc[mi][ni];
            float m = fmaxf(fmaxf(a[0], a[1]), fmaxf(a[2], a[3]));
            if (ok) {
                int cout = msup * 64 + mi * 16 + ln;
                unsigned short h = f2bf(fmaxf(m + sb[cout], 0.f));
                int py = yp0 + ypl;
                Yp[(((size_t)img * HPO + py + 1) * WPO + xg + 1) * COUT + cout] = (short)h;
            }
        }
    }
}

// ---------------------------------------------------------------------------
// conv4: image in LDS (CSTR=136), weight frags from global, ping-pong prefetch,
// no K-loop barriers, reg-pool epilogue -> f4 NHWC f32 (400,25,512).
// ---------------------------------------------------------------------------
__global__ __launch_bounds__(256, 2)
void conv4_mfma_kernel(const short* __restrict__ X3p, const short* __restrict__ W4t,
                       const float* __restrict__ bias, float* __restrict__ f4)
{
    constexpr int CSTR = 136;
    __shared__ short sx[144 * CSTR];     // 39,168 B
    __shared__ float sb[128];

    const int tid = threadIdx.x;
    const int img = blockIdx.x >> 2, mb = blockIdx.x & 3;
    const int wv = tid >> 6, lane = tid & 63, quad = lane >> 4, ln = lane & 15;
    const int msup = wv >> 1, nsup = wv & 1;

    const short* xsrc = X3p + (size_t)img * (144 * 128);
    for (int i = tid; i < 144 * 16; i += 256) {
        int pc = i >> 4, g = i & 15;
        uint4 v = *(const uint4*)(xsrc + pc * 128 + g * 8);
        *(uint4*)(&sx[pc * CSTR + g * 8]) = v;
    }
    for (int i = tid; i < 128; i += 256) sb[i] = bias[mb * 128 + i];

    int pbase[4];
    #pragma unroll
    for (int ni = 0; ni < 4; ++ni) {
        int q = nsup * 64 + ni * 16 + ln;
        int pc = (q < 100) ? q : 99;
        int yp = pc / 20, rem = pc % 20;
        int y = 2 * yp + (rem & 1), x = rem >> 1;
        pbase[ni] = ((y * 12 + x) * CSTR + quad * 8) * 2;
    }

    f32x4 acc[4][4];
    #pragma unroll
    for (int mi = 0; mi < 4; ++mi)
        #pragma unroll
        for (int ni = 0; ni < 4; ++ni) acc[mi][ni] = (f32x4)0.f;

    auto loadAF = [&](bf16x8* dst, int kc) {
        #pragma unroll
        for (int mi = 0; mi < 4; ++mi)
            dst[mi] = *(const bf16x8*)(W4t + ((size_t)kc * 512 + mb * 128 + msup * 64 + mi * 16 + ln) * 40 + quad * 8);
    };
    auto loadBF = [&](bf16x8* dst, int kc) {
        const int tap = kc >> 2, cb = (kc & 3) * 32;
        const int ky = tap / 3, kx = tap % 3;
        const int koff = ((ky * 12 + kx) * CSTR + cb) * 2;
        #pragma unroll
        for (int ni = 0; ni < 4; ++ni)
            dst[ni] = *(const bf16x8*)((const char*)sx + pbase[ni] + koff);
    };

    __syncthreads();   // sx/sb ready — the ONLY barrier

    bf16x8 afA[4], afB[4], bfA[4], bfB[4];
    loadAF(afA, 0); loadBF(bfA, 0);
    for (int kc = 0; kc < 36; kc += 2) {
        loadAF(afB, kc + 1); loadBF(bfB, kc + 1);
        #pragma unroll
        for (int mi = 0; mi < 4; ++mi)
            #pragma unroll
            for (int ni = 0; ni < 4; ++ni)
                acc[mi][ni] = __builtin_amdgcn_mfma_f32_16x16x32_bf16(bfA[ni], afA[mi], acc[mi][ni], 0, 0, 0);
        if (kc + 2 < 36) { loadAF(afA, kc + 2); loadBF(bfA, kc + 2); }
        #pragma unroll
        for (int mi = 0; mi < 4; ++mi)
            #pragma unroll
            for (int ni = 0; ni < 4; ++ni)
                acc[mi][ni] = __builtin_amdgcn_mfma_f32_16x16x32_bf16(bfB[ni], afB[mi], acc[mi][ni], 0, 0, 0);
    }

    // epilogue: pool = fmax of 4 acc regs; one f32 store per lane (64B/quad)
    #pragma unroll
    for (int ni = 0; ni < 4; ++ni) {
        int g = nsup * 16 + ni * 4 + quad;
        bool ok = (g < 25);
        #pragma unroll
        for (int mi = 0; mi < 4; ++mi) {
            f32x4 a = acc[mi][ni];
            float m = fmaxf(fmaxf(a[0], a[1]), fmaxf(a[2], a[3]));
            if (ok) {
                int cl = msup * 64 + mi * 16 + ln;
                f4[((size_t)img * 25 + g) * 512 + mb * 128 + cl] = fmaxf(m + sb[cl], 0.f);
            }
        }
    }
}

// ---------------------------------------------------------------------------
// heads (f4 NHWC f32 (400,25,512) -> g, proto, predict, cls)
// ---------------------------------------------------------------------------
__global__ __launch_bounds__(256)
void gap_kernel(const float* __restrict__ f4, float* __restrict__ g)
{
    const int img = blockIdx.x;
    for (int c = threadIdx.x; c < 512; c += 256) {
        float s = 0.f;
        #pragma unroll
        for (int p = 0; p < 25; ++p)
            s += f4[((size_t)img * 25 + p) * 512 + c];
        g[(size_t)img * 512 + c] = s * (1.f / 25.f);
    }
}

__global__ __launch_bounds__(256)
void proto_kernel(const float* __restrict__ g, const float* __restrict__ ytrain,
                  float* __restrict__ proto)
{
    const int b = blockIdx.x / 5, k = blockIdx.x % 5;
    __shared__ float sp[512];
    __shared__ float red[256];

    float yv[25];
    float cnt = 0.f;
    for (int n = 0; n < 25; ++n) {
        yv[n] = ytrain[(size_t)(b * 25 + n) * 5 + k];
        cnt += yv[n];
    }
    const float icnt = 1.f / cnt;

    for (int c = threadIdx.x; c < 512; c += 256) {
        float s = 0.f;
        for (int n = 0; n < 25; ++n)
            s += yv[n] * g[((size_t)(b * 25 + n)) * 512 + c];
        sp[c] = s * icnt;
    }
    __syncthreads();

    float ss = 0.f;
    for (int c = threadIdx.x; c < 512; c += 256) ss += sp[c] * sp[c];
    red[threadIdx.x] = ss;
    __syncthreads();
    for (int s = 128; s > 0; s >>= 1) {
        if (threadIdx.x < s) red[threadIdx.x] += red[threadIdx.x + s];
        __syncthreads();
    }
    const float inv = 1.f / fmaxf(sqrtf(red[0]), 1e-12f);
    for (int c = threadIdx.x; c < 512; c += 256)
        proto[((size_t)(b * 5 + k)) * 512 + c] = sp[c] * inv;
}

__global__ __launch_bounds__(64)
void predict_kernel(const float* __restrict__ g, const float* __restrict__ wc,
                    const float* __restrict__ bc, float* __restrict__ out)
{
    const int q = blockIdx.x;
    __shared__ float fq[512];
    const float* gq = g + (size_t)(100 + q) * 512;
    float ss = 0.f;
    for (int c = threadIdx.x; c < 512; c += 64) {
        const float v = gq[c];
        fq[c] = v;
        ss += v * v;
    }
    #pragma unroll
    for (int o = 32; o > 0; o >>= 1) ss += __shfl_down(ss, o);
    const float inv = 1.f / fmaxf(sqrtf(__shfl(ss, 0)), 1e-12f);
    __syncthreads();

    const int m = threadIdx.x;
    float s = bc[m];
    for (int c = 0; c < 512; ++c)
        s = fmaf(fq[c] * inv, wc[m * 512 + c], s);
    out[q * 64 + m] = s;
}

__global__ __launch_bounds__(256)
void cls_kernel(const float* __restrict__ f4, const float* __restrict__ proto,
                float* __restrict__ outc)
{
    __shared__ float sf[25 * 516];      // +4 pad kills 512-stride bank conflicts
    __shared__ float spr[5 * 516];
    const int q = blockIdx.x, b = q / 75;
    const float* f = f4 + (size_t)(100 + q) * (25 * 512);
    for (int i = threadIdx.x; i < 3200; i += 256) {
        int row = i >> 7, col = i & 127;
        *(float4*)(&sf[row * 516 + col * 4]) = *(const float4*)(f + row * 512 + col * 4);
    }
    const float* pb = proto + (size_t)b * 5 * 512;
    for (int i = threadIdx.x; i < 640; i += 256) {
        int row = i >> 7, col = i & 127;
        *(float4*)(&spr[row * 516 + col * 4]) = *(const float4*)(pb + row * 512 + col * 4);
    }
    __syncthreads();

    for (int it = threadIdx.x; it < 125; it += 256) {
        int i = it / 25, p = it % 25;
        const float* fp = &sf[p * 516];
        const float* pr = &spr[i * 516];
        float ss = 0.f, dot = 0.f;
        for (int c = 0; c < 512; c += 4) {
            float4 v = *(const float4*)(fp + c);
            float4 w = *(const float4*)(pr + c);
            ss  += v.x * v.x + v.y * v.y + v.z * v.z + v.w * v.w;
            dot += v.x * w.x + v.y * w.y + v.z * w.z + v.w * w.w;
        }
        outc[(size_t)q * 125 + it] = dot / fmaxf(sqrtf(ss), 1e-12f);
    }
}

// ---------------------------------------------------------------------------
extern "C" void kernel_launch(void* const* d_in, const int* in_sizes, int n_in,
                              void* d_out, int out_size, void* d_ws, size_t ws_size,
                              hipStream_t stream)
{
    (void)in_sizes; (void)n_in; (void)out_size; (void)ws_size;
    const float* xtrain = (const float*)d_in[0];
    const float* xtest  = (const float*)d_in[1];
    const float* ytrain = (const float*)d_in[2];
    const float* w1 = (const float*)d_in[4];
    const float* b1 = (const float*)d_in[5];
    const float* w2 = (const float*)d_in[6];
    const float* b2 = (const float*)d_in[7];
    const float* w3 = (const float*)d_in[8];
    const float* b3 = (const float*)d_in[9];
    const float* w4 = (const float*)d_in[10];
    const float* b4 = (const float*)d_in[11];
    const float* wc = (const float*)d_in[12];
    const float* bc = (const float*)d_in[13];

    char* ws = (char*)d_ws;
    short* X1p = (short*)(ws + OFF_X1P);
    short* X2p = (short*)(ws + OFF_X2P);
    short* X3p = (short*)(ws + OFF_X3P);
    short* W1t = (short*)(ws + OFF_W1T);
    short* W2t = (short*)(ws + OFF_W2T);
    short* W3t = (short*)(ws + OFF_W3T);
    short* W4t = (short*)(ws + OFF_W4T);
    float* f4    = (float*)(ws + OFF_F4);
    float* g     = (float*)(ws + OFF_G);
    float* proto = (float*)(ws + OFF_PROTO);
    float* out = (float*)d_out;

    // zero only the pad rings of the padded activation buffers
    border_zero_kernel<44, 44, 64><<<400, 256, 0, stream>>>(X1p);
    border_zero_kernel<23, 23, 64><<<400, 256, 0, stream>>>(X2p);
    border_zero_kernel<12, 12, 128><<<400, 256, 0, stream>>>(X3p);

    // weight transforms
    wt1_kernel<<<20, 256, 0, stream>>>(w1, W1t);
    wt_tap_kernel<64, 64><<<144, 256, 0, stream>>>(w2, W2t);
    wt_tap_kernel<128, 64><<<288, 256, 0, stream>>>(w3, W3t);
    wt_tap_kernel<512, 128><<<2304, 256, 0, stream>>>(w4, W4t);

    // backbone
    conv1_mfma_kernel<<<400 * 14, 256, 0, stream>>>(xtrain, xtest, W1t, b1, X1p);
    //                CIN COUT NWM NWN MT NT YPB WOUT HPIN WPIN HPO WPO RBI
    conv_mfma_kernel< 64,  64,  1,  4, 4, 4,  3,  42,  44,  44, 23, 23,  7>
        <<<400 * 7, 256, 0, stream>>>(X1p, W2t, b2, X2p);
    conv_mfma_kernel< 64, 128,  2,  2, 4, 7,  5,  21,  23,  23, 12, 12,  2>
        <<<400 * 2, 256, 0, stream>>>(X2p, W3t, b3, X3p);
    conv4_mfma_kernel<<<400 * 4, 256, 0, stream>>>(X3p, W4t, b4, f4);

    // heads
    gap_kernel<<<400, 256, 0, stream>>>(f4, g);
    proto_kernel<<<20, 256, 0, stream>>>(g, ytrain, proto);
    predict_kernel<<<300, 64, 0, stream>>>(g, wc, bc, out);
    cls_kernel<<<300, 256, 0, stream>>>(f4, proto, out + 19200);
}